// Round 6
// baseline (508.456 us; speedup 1.0000x reference)
//
#include <hip/hip_runtime.h>

#define EPSV 1e-5f

typedef short bf16x8 __attribute__((ext_vector_type(8)));
typedef float f32x4 __attribute__((ext_vector_type(4)));

__device__ __forceinline__ float sigmoidf_(float x) {
  return 1.f / (1.f + __expf(-x));
}
__device__ __forceinline__ unsigned short f2bf(float f) {
  unsigned int u = __float_as_uint(f);
  u += 0x7fffu + ((u >> 16) & 1u);
  return (unsigned short)(u >> 16);
}
__device__ __forceinline__ float bfu(unsigned short h) {
  union { unsigned int u; float f; } t; t.u = ((unsigned int)h) << 16; return t.f;
}
__device__ __forceinline__ float bflo(unsigned int u) {
  union { unsigned int x; float f; } t; t.x = u << 16; return t.f;
}
__device__ __forceinline__ float bfhi(unsigned int u) {
  union { unsigned int x; float f; } t; t.x = u & 0xffff0000u; return t.f;
}

// ---------------------------------------------------------------------------
// W_comb[i][m][k] = sum_j fusion_W[p][m][d*64+j] * out_W[i][j][k]
// ---------------------------------------------------------------------------
__global__ __launch_bounds__(256) void precomp_wc(
    const float* __restrict__ fW,   // (2,64,128)
    const float* __restrict__ oW,   // (4,64,128)
    float* __restrict__ Wc)         // (4,64,128)
{
  const int bi = blockIdx.x;
  const int i = bi >> 3, mg = bi & 7;
  const int m = (mg << 3) + (threadIdx.x >> 5);
  const int k0 = (threadIdx.x & 31) << 2;
  const int p = i >> 1, d = i & 1;
  const float* fr = fW + p * 8192 + m * 128 + d * 64;
  const float* orow = oW + i * 8192 + k0;
  float a0 = 0.f, a1 = 0.f, a2 = 0.f, a3 = 0.f;
  for (int j = 0; j < 64; ++j) {
    const float f = fr[j];
    const float4 o4 = *(const float4*)(orow + j * 128);
    a0 += f * o4.x; a1 += f * o4.y; a2 += f * o4.z; a3 += f * o4.w;
  }
  float* out = Wc + i * 8192 + m * 128 + k0;
  out[0] = a0; out[1] = a1; out[2] = a2; out[3] = a3;
}

// ---------------------------------------------------------------------------
// Wc -> bf16 MFMA B-fragment order: WcF[ip][tile(4)][h(4)][lane(64)][8]
// ---------------------------------------------------------------------------
__global__ __launch_bounds__(256) void precomp_wcf(
    const float* __restrict__ Wc, unsigned short* __restrict__ WcF)
{
  const int ip = blockIdx.x;
  const float* src = Wc + (size_t)ip * 8192;
  unsigned short* dst = WcF + (size_t)ip * 8192;
  for (int idx = threadIdx.x; idx < 8192; idx += 256) {
    const int tile = idx >> 11;
    const int h = (idx >> 9) & 3;
    const int lane = (idx >> 3) & 63;
    const int j = idx & 7;
    const int col = lane & 15, quad = lane >> 4;
    dst[idx] = f2bf(src[(tile * 16 + col) * 128 + h * 32 + quad * 8 + j]);
  }
}

// ---------------------------------------------------------------------------
// in_proj weights -> bf16 in MFMA B-fragment order (1KB coalesced per wave).
// ---------------------------------------------------------------------------
__global__ __launch_bounds__(256) void precomp_wpf(
    const float* __restrict__ Wp, unsigned short* __restrict__ WpF)
{
  const int ip = blockIdx.x;
  const float* src = Wp + (size_t)ip * 24704;
  unsigned short* dst = WpF + (size_t)ip * 25600;
  for (int idx = threadIdx.x; idx < 25600; idx += 256) {
    const int tile = idx >> 10;
    const int rem = idx & 1023;
    const int h = rem >> 9;
    const int lane = (rem >> 3) & 63;
    const int j = idx & 7;
    const int col = lane & 15, quad = lane >> 4;
    const int o = tile * 16 + col;
    const int k = h * 32 + quad * 8 + j;
    dst[idx] = (o < 386) ? f2bf(src[o * 64 + k]) : (unsigned short)0;
  }
}

// ---------------------------------------------------------------------------
// transp0: x0[b][t][f][c] = x[b][c][t][f]
// ---------------------------------------------------------------------------
__global__ __launch_bounds__(256) void transp0(
    const float* __restrict__ x, float* __restrict__ x0)
{
  __shared__ float T[64 * 132];
  const int tid = threadIdx.x, blk = blockIdx.x;
  const int b = blk >> 7, t = blk & 127;
  {
    const int c = tid >> 2, f0 = (tid & 3) << 5;
    const float* xp = x + (((size_t)(b * 64 + c) * 128 + t) << 7) + f0;
    float* tp = &T[c * 132 + f0];
    #pragma unroll
    for (int j = 0; j < 8; ++j)
      *(float4*)(tp + (j << 2)) = *(const float4*)(xp + (j << 2));
  }
  __syncthreads();
  {
    const int f = tid >> 1, cb = (tid & 1) << 5;
    float* op = x0 + (((size_t)(b * 128 + t) * 128 + f) << 6) + cb;
    #pragma unroll
    for (int j = 0; j < 32; j += 4) {
      float4 v;
      v.x = T[(cb + j + 0) * 132 + f];
      v.y = T[(cb + j + 1) * 132 + f];
      v.z = T[(cb + j + 2) * 132 + f];
      v.w = T[(cb + j + 3) * 132 + f];
      *(float4*)(op + j) = v;
    }
  }
}

// ---------------------------------------------------------------------------
// One block = one (sequence, direction). Chunked-SSD, 16-step chunks — the
// R1-measured schedule (134 us/dispatch), unchanged. Single fix vs R1:
// __launch_bounds__(512, 2) -> VGPR cap 128 (hipcc arg2 = min blocks/CU).
// R1's (512,4) capped at 64 VGPR and spilled ~36 MB/dispatch to scratch
// (WRITE_SIZE 48.8 MB vs 16.4 MB algorithmic). LDS 73.5 KB already limits
// occupancy to 2 blocks/CU (grid = 4 blocks/CU -> balanced 2+2 rounds), so
// the relaxed cap costs nothing.
// ---------------------------------------------------------------------------
__global__ __launch_bounds__(512, 2) void mamba_dir(
    const float* __restrict__ src,   // [seq][pos][c] f32 (x0 or x1)
    unsigned short* __restrict__ ybuf, // bf16 [dir][seq][pos][64]
    const unsigned short* __restrict__ WpF, // bf16 fragments (4,25600)
    const unsigned short* __restrict__ WcF, // bf16 fragments (4,8192)
    const float* __restrict__ cwA, const float* __restrict__ cbA,
    const float* __restrict__ dtbA, const float* __restrict__ AlA,
    const float* __restrict__ DpA, const float* __restrict__ nwA,
    const float* __restrict__ lnwA, const float* __restrict__ lnbA,
    int phase)
{
  __shared__ __align__(16) unsigned short sU[16 * 72];    // LN'd u (A-frag)
  __shared__ __align__(16) unsigned short sZb[16 * 136];  // z, then g
  __shared__ __align__(16) float sZx[16 * 260];           // raw xBC; y in cols 0-127
  __shared__ __align__(16) unsigned short sBC16[16 * 136];// bf16 B(0-63) C(64-127) row-major
  __shared__ __align__(16) unsigned short sXdT[128 * 40]; // bf16 x^T [c][t], t>=16 zero
  __shared__ __align__(16) unsigned short sXwT[128 * 40]; // bf16 (w_t*x)^T [c][t]
  __shared__ __align__(16) unsigned short sBT[64 * 40];   // bf16 B^T [n][t], t>=16 zero
  __shared__ __align__(16) unsigned short sSm[2 * 16 * 40]; // bf16 masked scores [h][t][s]
  __shared__ __align__(16) unsigned short sH[2 * 64 * 72];  // bf16 h snapshot [h][p][n]
  __shared__ float sMeta[16][2][4];                       // per (t,h): {L, dt, w, P}
  __shared__ float sDtRaw[16][2];

  const int tid = threadIdx.x;
  const int blk = blockIdx.x;
  const int seq = blk >> 1, dir = blk & 1;
  const int ip = (phase << 1) + dir;
  const float dtb0 = dtbA[ip * 2], dtb1 = dtbA[ip * 2 + 1];
  const float nA0 = -__expf(AlA[ip * 2]), nA1 = -__expf(AlA[ip * 2 + 1]);
  const float Dp0 = DpA[ip * 2], Dp1 = DpA[ip * 2 + 1];
  const int c256 = tid & 255;                 // conv channel
  const int lh = tid >> 8;                    // conv lt-half
  const float4 cw4 = *(const float4*)(cwA + ip * 1024 + (c256 << 2));
  const float cbias = cbA[ip * 256 + c256];
  float ch0 = 0.f, ch1 = 0.f, ch2 = 0.f;      // conv carry (lh==0 only)

  const int wv = tid >> 6, lane = tid & 63;
  const int col = lane & 15, quad = lane >> 4;

  f32x4 hacc[8];                              // h state (waves 0-3): f32 accumulators
  #pragma unroll
  for (int i = 0; i < 8; ++i) hacc[i] = (f32x4){0.f, 0.f, 0.f, 0.f};

  // zero fragment arrays once: K-pad regions must stay 0; sH = initial state 0
  {
    unsigned int* z;
    z = (unsigned int*)sXdT; for (int i = tid; i < 2560; i += 512) z[i] = 0u;
    z = (unsigned int*)sXwT; for (int i = tid; i < 2560; i += 512) z[i] = 0u;
    z = (unsigned int*)sBT;  for (int i = tid; i < 1280; i += 512) z[i] = 0u;
    z = (unsigned int*)sSm;  for (int i = tid; i < 640;  i += 512) z[i] = 0u;
    z = (unsigned int*)sH;   for (int i = tid; i < 4608; i += 512) z[i] = 0u;
  }

  const unsigned short* wf = WpF + (size_t)ip * 25600;
  const unsigned short* wcf = WcF + (size_t)ip * 8192;
  const size_t sb = (size_t)seq << 13;
  const int pos = tid >> 6, lc = tid & 63;    // load/LN mapping
  const int lnb_i = (phase << 6) + lc;
  const float lnw_v = lnwA[lnb_i], lnb_v = lnbA[lnb_i];

  // preload chunk 0 (2 floats/thread, coalesced)
  float vc0, vc1;
  {
    const int p0 = dir ? (127 - pos) : pos;
    const int p1 = dir ? (127 - (pos + 8)) : (pos + 8);
    vc0 = src[sb + (size_t)p0 * 64 + lc];
    vc1 = src[sb + (size_t)p1 * 64 + lc];
  }

  for (int ck = 0; ck < 8; ++ck) {
    // ---- prefetch next chunk ----
    float vn0 = 0.f, vn1 = 0.f;
    if (ck < 7) {
      const int st0 = ((ck + 1) << 4) + pos;
      const int p0 = dir ? (127 - st0) : st0;
      const int p1 = dir ? (127 - (st0 + 8)) : (st0 + 8);
      vn0 = src[sb + (size_t)p0 * 64 + lc];
      vn1 = src[sb + (size_t)p1 * 64 + lc];
    }
    // ---- 1+2. layernorm in registers (wave-shfl), write bf16 sU ----
    #pragma unroll
    for (int half = 0; half < 2; ++half) {
      const float v = half ? vc1 : vc0;
      float sm = v, s2 = v * v;
      sm += __shfl_xor(sm, 1);  s2 += __shfl_xor(s2, 1);
      sm += __shfl_xor(sm, 2);  s2 += __shfl_xor(s2, 2);
      sm += __shfl_xor(sm, 4);  s2 += __shfl_xor(s2, 4);
      sm += __shfl_xor(sm, 8);  s2 += __shfl_xor(s2, 8);
      sm += __shfl_xor(sm, 16); s2 += __shfl_xor(s2, 16);
      sm += __shfl_xor(sm, 32); s2 += __shfl_xor(s2, 32);
      const float mean = sm * (1.f / 64.f);
      const float inv = rsqrtf(s2 * (1.f / 64.f) - mean * mean + EPSV);
      sU[(pos + half * 8) * 72 + lc] = f2bf((v - mean) * inv * lnw_v + lnb_v);
    }
    __syncthreads();   // B1: sU ready; guards sZb/sZx vs prior step-7/3 reads
    // ---- 3. in_proj via MFMA; B fragments streamed from global/L2 ----
    {
      const int wave = tid >> 6;
      const bf16x8 a0 = *(const bf16x8*)(&sU[col * 72 + quad * 8]);
      const bf16x8 a1 = *(const bf16x8*)(&sU[col * 72 + quad * 8 + 32]);
      for (int tile = wave; tile < 25; tile += 8) {
        const unsigned short* wt = wf + (tile << 10) + (lane << 3);
        const bf16x8 b0 = *(const bf16x8*)(wt);
        const bf16x8 b1 = *(const bf16x8*)(wt + 512);
        f32x4 d = {0.f, 0.f, 0.f, 0.f};
        d = __builtin_amdgcn_mfma_f32_16x16x32_bf16(a0, b0, d, 0, 0, 0);
        d = __builtin_amdgcn_mfma_f32_16x16x32_bf16(a1, b1, d, 0, 0, 0);
        const int o = (tile << 4) + col;
        if (tile < 8) {               // z -> bf16
          #pragma unroll
          for (int r = 0; r < 4; ++r)
            sZb[(quad * 4 + r) * 136 + o] = f2bf(d[r]);
        } else if (tile < 24) {       // xBC -> f32
          #pragma unroll
          for (int r = 0; r < 4; ++r)
            sZx[(quad * 4 + r) * 260 + (o - 128)] = d[r];
        } else if (col < 2) {         // dt raw (o = 384,385)
          #pragma unroll
          for (int r = 0; r < 4; ++r)
            sDtRaw[quad * 4 + r][col] = d[r];
        }
      }
    }
    __syncthreads();   // B2
    // ---- 4. conv(4,causal)+silu -> bf16 fragment layouts; dt/L meta ----
    {
      const int c = c256;
      float a0c, a1c, a2c;
      if (lh == 0) { a0c = ch0; a1c = ch1; a2c = ch2; }
      else {
        a0c = sZx[5 * 260 + c];
        a1c = sZx[6 * 260 + c];
        a2c = sZx[7 * 260 + c];
      }
      const int lt0 = lh << 3;
      unsigned int pkv[4];
      #pragma unroll
      for (int l = 0; l < 8; ++l) {
        const int lt = lt0 + l;
        const float a3 = sZx[lt * 260 + c];
        const float acc = cbias + a0c * cw4.x + a1c * cw4.y + a2c * cw4.z + a3 * cw4.w;
        const float sv = acc * sigmoidf_(acc);
        const unsigned int hv = (unsigned int)f2bf(sv);
        if (c >= 192)      sBC16[lt * 136 + 64 + (c - 192)] = (unsigned short)hv;
        else if (c >= 128) sBC16[lt * 136 + (c - 128)] = (unsigned short)hv;
        if (l & 1) pkv[l >> 1] |= hv << 16; else pkv[l >> 1] = hv;
        a0c = a1c; a1c = a2c; a2c = a3;
      }
      if (c < 128)
        *(uint4*)(&sXdT[c * 40 + lt0]) = make_uint4(pkv[0], pkv[1], pkv[2], pkv[3]);
      else if (c < 192)
        *(uint4*)(&sBT[(c - 128) * 40 + lt0]) = make_uint4(pkv[0], pkv[1], pkv[2], pkv[3]);
      if (lh == 0) {   // carry = raw xBC at lt 13,14,15
        ch0 = sZx[13 * 260 + c];
        ch1 = sZx[14 * 260 + c];
        ch2 = sZx[15 * 260 + c];
      }
      if (tid < 32) {
        const int lt = tid >> 1, hh = tid & 1;
        const float rawv = sDtRaw[lt][hh] + (hh ? dtb1 : dtb0);
        const float dtv = (rawv > 20.f) ? rawv : log1pf(__expf(rawv));
        float Lx = dtv * (hh ? nA1 : nA0);   // log dA_t
        #pragma unroll
        for (int d = 2; d < 32; d <<= 1) {   // inclusive prefix over lt (stride-2 lanes)
          const float tpv = __shfl_up(Lx, d);
          Lx += (tid >= d) ? tpv : 0.f;
        }
        const float Ltot = __shfl(Lx, 30 + hh);
        *(float4*)(&sMeta[lt][hh][0]) =
            make_float4(Lx, dtv, __expf(Ltot - Lx) * dtv, __expf(Lx));
      }
    }
    __syncthreads();   // B3
    // ---- 5a. G+mask (w0) | Xw fixup (w1-2) | y_inter (w4-7) ----
    f32x4 yD0, yD1;
    if (wv == 0) {
      const bf16x8 ca0 = *(const bf16x8*)(&sBC16[col * 136 + 64 + quad * 8]);
      const bf16x8 ca1 = *(const bf16x8*)(&sBC16[col * 136 + 96 + quad * 8]);
      const bf16x8 bb0 = *(const bf16x8*)(&sBC16[col * 136 + quad * 8]);
      const bf16x8 bb1 = *(const bf16x8*)(&sBC16[col * 136 + 32 + quad * 8]);
      f32x4 g = {0.f, 0.f, 0.f, 0.f};
      g = __builtin_amdgcn_mfma_f32_16x16x32_bf16(ca0, bb0, g, 0, 0, 0);
      g = __builtin_amdgcn_mfma_f32_16x16x32_bf16(ca1, bb1, g, 0, 0, 0);
      // D: row t = quad*4+r, col s = lane&15
      #pragma unroll
      for (int h = 0; h < 2; ++h) {
        const float Ls = sMeta[col][h][0];
        const float dts = sMeta[col][h][1];
        #pragma unroll
        for (int r = 0; r < 4; ++r) {
          const int t = quad * 4 + r;
          const float m = (col <= t) ? __expf(sMeta[t][h][0] - Ls) * dts : 0.f;
          sSm[(h * 16 + t) * 40 + col] = f2bf(g[r] * m);
        }
      }
    } else if (wv <= 2) {
      if (ck < 7) {     // Xw = w_t * x (feeds h-update only)
        const int p = ((wv - 1) << 6) + lane;
        const int hh = p >> 6;
        #pragma unroll
        for (int tp = 0; tp < 8; ++tp) {
          const unsigned int xr = *(const unsigned int*)(&sXdT[p * 40 + tp * 2]);
          const unsigned int lo = (unsigned int)f2bf(bflo(xr) * sMeta[tp * 2][hh][2]);
          const unsigned int hi = (unsigned int)f2bf(bfhi(xr) * sMeta[tp * 2 + 1][hh][2]);
          *(unsigned int*)(&sXwT[p * 40 + tp * 2]) = lo | (hi << 16);
        }
      }
    } else if (wv >= 4) {
      // y_inter[t,p] = P_t * sum_n C[t,n] h_prev[p,n]
      const int h = (wv - 4) >> 1, pt2 = (wv - 4) & 1;
      const bf16x8 ca0 = *(const bf16x8*)(&sBC16[col * 136 + 64 + quad * 8]);
      const bf16x8 ca1 = *(const bf16x8*)(&sBC16[col * 136 + 96 + quad * 8]);
      const unsigned short* hp0 = &sH[(h * 64 + pt2 * 32 + col) * 72];
      const unsigned short* hp1 = hp0 + 16 * 72;
      const bf16x8 h00 = *(const bf16x8*)(hp0 + quad * 8);
      const bf16x8 h01 = *(const bf16x8*)(hp0 + 32 + quad * 8);
      const bf16x8 h10 = *(const bf16x8*)(hp1 + quad * 8);
      const bf16x8 h11 = *(const bf16x8*)(hp1 + 32 + quad * 8);
      yD0 = (f32x4){0.f, 0.f, 0.f, 0.f};
      yD1 = (f32x4){0.f, 0.f, 0.f, 0.f};
      yD0 = __builtin_amdgcn_mfma_f32_16x16x32_bf16(ca0, h00, yD0, 0, 0, 0);
      yD0 = __builtin_amdgcn_mfma_f32_16x16x32_bf16(ca1, h01, yD0, 0, 0, 0);
      yD1 = __builtin_amdgcn_mfma_f32_16x16x32_bf16(ca0, h10, yD1, 0, 0, 0);
      yD1 = __builtin_amdgcn_mfma_f32_16x16x32_bf16(ca1, h11, yD1, 0, 0, 0);
      #pragma unroll
      for (int r = 0; r < 4; ++r) {
        const float Pv = sMeta[quad * 4 + r][h][3];
        yD0[r] *= Pv; yD1[r] *= Pv;
      }
    }
    __syncthreads();   // B4
    // ---- 5b. h-update (w0-3) | y_intra + D*x + y write (w4-7) ----
    if (wv < 4) {
      if (ck < 7) {
        const int h = wv >> 1, ph = wv & 1;
        const int pb = h * 64 + ph * 32;       // global x-channel base
        const float At = sMeta[15][h][3];      // exp(Ltot)
        const bf16x8 xa0 = *(const bf16x8*)(&sXwT[(pb + col) * 40 + quad * 8]);
        const bf16x8 xa1 = *(const bf16x8*)(&sXwT[(pb + 16 + col) * 40 + quad * 8]);
        #pragma unroll
        for (int nt = 0; nt < 4; ++nt) {
          const bf16x8 bbt = *(const bf16x8*)(&sBT[(nt * 16 + col) * 40 + quad * 8]);
          #pragma unroll
          for (int r = 0; r < 4; ++r) { hacc[nt][r] *= At; hacc[nt + 4][r] *= At; }
          hacc[nt]     = __builtin_amdgcn_mfma_f32_16x16x32_bf16(xa0, bbt, hacc[nt], 0, 0, 0);
          hacc[nt + 4] = __builtin_amdgcn_mfma_f32_16x16x32_bf16(xa1, bbt, hacc[nt + 4], 0, 0, 0);
        }
        // snapshot h -> sH bf16 for next chunk's y_inter
        #pragma unroll
        for (int nt = 0; nt < 4; ++nt) {
          #pragma unroll
          for (int r = 0; r < 4; ++r) {
            sH[(pb + quad * 4 + r) * 72 + nt * 16 + col] = f2bf(hacc[nt][r]);
            sH[(pb + 16 + quad * 4 + r) * 72 + nt * 16 + col] = f2bf(hacc[nt + 4][r]);
          }
        }
      }
    } else {
      const int h = (wv - 4) >> 1, pt2 = (wv - 4) & 1;
      const int cb0 = h * 64 + pt2 * 32;
      const float dp = h ? Dp1 : Dp0;
      const bf16x8 sa = *(const bf16x8*)(&sSm[(h * 16 + col) * 40 + quad * 8]);
      const bf16x8 xb0 = *(const bf16x8*)(&sXdT[(cb0 + col) * 40 + quad * 8]);
      const bf16x8 xb1 = *(const bf16x8*)(&sXdT[(cb0 + 16 + col) * 40 + quad * 8]);
      yD0 = __builtin_amdgcn_mfma_f32_16x16x32_bf16(sa, xb0, yD0, 0, 0, 0);
      yD1 = __builtin_amdgcn_mfma_f32_16x16x32_bf16(sa, xb1, yD1, 0, 0, 0);
      // + Dp * x (x[t,c] from transposed bf16, 4 consecutive t = one b64)
      const uint2 xw0 = *(const uint2*)(&sXdT[(cb0 + col) * 40 + quad * 4]);
      const uint2 xw1 = *(const uint2*)(&sXdT[(cb0 + 16 + col) * 40 + quad * 4]);
      yD0[0] += dp * bflo(xw0.x); yD0[1] += dp * bfhi(xw0.x);
      yD0[2] += dp * bflo(xw0.y); yD0[3] += dp * bfhi(xw0.y);
      yD1[0] += dp * bflo(xw1.x); yD1[1] += dp * bfhi(xw1.x);
      yD1[2] += dp * bflo(xw1.y); yD1[3] += dp * bfhi(xw1.y);
      #pragma unroll
      for (int r = 0; r < 4; ++r) {
        sZx[(quad * 4 + r) * 260 + cb0 + col] = yD0[r];
        sZx[(quad * 4 + r) * 260 + cb0 + 16 + col] = yD1[r];
      }
    }
    __syncthreads();   // B5
    // ---- 6. gate with silu(z) + rmsnorm -> bf16 g IN PLACE over z (sZb) ----
    {
      const int w = tid >> 6, kk = tid & 63, k0 = kk << 1;
      #pragma unroll
      for (int sub = 0; sub < 2; ++sub) {
        const int lt = w + (sub << 3);
        const float2 yv = *(const float2*)(&sZx[lt * 260 + k0]);
        const unsigned int zp = *(const unsigned int*)(&sZb[lt * 136 + k0]);
        const float z0 = bflo(zp), z1 = bfhi(zp);
        const float g0 = yv.x * (z0 * sigmoidf_(z0));
        const float g1 = yv.y * (z1 * sigmoidf_(z1));
        float ssq = g0 * g0 + g1 * g1;
        ssq += __shfl_xor(ssq, 1);
        ssq += __shfl_xor(ssq, 2);
        ssq += __shfl_xor(ssq, 4);
        ssq += __shfl_xor(ssq, 8);
        ssq += __shfl_xor(ssq, 16);
        ssq += __shfl_xor(ssq, 32);
        const float sc = rsqrtf(ssq * (1.f / 128.f) + EPSV);
        const float2 nw2 = *(const float2*)(nwA + ip * 128 + k0);
        const unsigned int lo = f2bf(g0 * sc * nw2.x);
        const unsigned int hi = f2bf(g1 * sc * nw2.y);
        *(unsigned int*)(&sZb[lt * 136 + k0]) = lo | (hi << 16);
      }
    }
    __syncthreads();   // B6
    // ---- 7. out-matmul via MFMA: g (16x128, A=sZb rows) @ WcF (4 m-tiles) ----
    {
      const int wave = tid >> 6;
      if (wave < 4) {
        const unsigned short* wt = wcf + (wave << 11);
        f32x4 d = {0.f, 0.f, 0.f, 0.f};
        #pragma unroll
        for (int h = 0; h < 4; ++h) {
          const bf16x8 a = *(const bf16x8*)(&sZb[col * 136 + (h << 5) + (quad << 3)]);
          const bf16x8 bb = *(const bf16x8*)(wt + (h << 9) + (lane << 3));
          d = __builtin_amdgcn_mfma_f32_16x16x32_bf16(a, bb, d, 0, 0, 0);
        }
        const size_t yb = ((size_t)(dir * 512 + seq) * 128) << 6;
        #pragma unroll
        for (int r = 0; r < 4; ++r) {
          const int pp = (quad << 2) + r;
          const int st = (ck << 4) + pp, rp = dir ? (127 - st) : st;
          ybuf[yb + ((size_t)rp << 6) + (wave << 4) + col] = f2bf(d[r]);
        }
      }
    }
    vc0 = vn0; vc1 = vn1;
  }
}

// ---------------------------------------------------------------------------
// combine0: x1[b][f][t][c] = x[b][c][t][f] + yf + yb + fb0[c]   (coalesced)
// ---------------------------------------------------------------------------
__global__ __launch_bounds__(256) void combine0(
    const float* __restrict__ x, const unsigned short* __restrict__ ybuf,
    const float* __restrict__ fb, float* __restrict__ x1)
{
  __shared__ float T[64 * 132];
  const int tid = threadIdx.x, blk = blockIdx.x;
  const int b = blk >> 7, t = blk & 127;
  {
    const int c = tid >> 2, f0 = (tid & 3) << 5;
    const float* xp = x + (((size_t)(b * 64 + c) * 128 + t) << 7) + f0;
    float* tp = &T[c * 132 + f0];
    #pragma unroll
    for (int j = 0; j < 8; ++j)
      *(float4*)(tp + (j << 2)) = *(const float4*)(xp + (j << 2));
  }
  __syncthreads();
  {
    const int f = tid >> 1, cb = (tid & 1) << 5;
    const size_t s0 = (size_t)b * 128 + t;
    const unsigned short* yf = ybuf + ((s0 * 128 + f) << 6) + cb;
    const unsigned short* yb = ybuf + (((s0 + 512) * 128 + f) << 6) + cb;
    float* op = x1 + (((size_t)(b * 128 + f) * 128 + t) << 6) + cb;
    #pragma unroll
    for (int j = 0; j < 32; j += 4) {
      float4 v;
      v.x = T[(cb + j + 0) * 132 + f] + bfu(yf[j + 0]) + bfu(yb[j + 0]) + fb[cb + j + 0];
      v.y = T[(cb + j + 1) * 132 + f] + bfu(yf[j + 1]) + bfu(yb[j + 1]) + fb[cb + j + 1];
      v.z = T[(cb + j + 2) * 132 + f] + bfu(yf[j + 2]) + bfu(yb[j + 2]) + fb[cb + j + 2];
      v.w = T[(cb + j + 3) * 132 + f] + bfu(yf[j + 3]) + bfu(yb[j + 3]) + fb[cb + j + 3];
      *(float4*)(op + j) = v;
    }
  }
}

// ---------------------------------------------------------------------------
// combine1: out[b][c][t][f] = x1[b][f][t][c] + yf + yb + fb1[c]  (coalesced)
// ---------------------------------------------------------------------------
__global__ __launch_bounds__(256) void combine1(
    const float* __restrict__ x1, const unsigned short* __restrict__ ybuf,
    const float* __restrict__ fb, float* __restrict__ out)
{
  __shared__ float T[128 * 68];
  const int tid = threadIdx.x, blk = blockIdx.x;
  const int b = blk >> 7, t = blk & 127;
  {
    const int f = tid >> 1, cb = (tid & 1) << 5;
    const size_t s1 = (size_t)b * 128 + f;
    const float* xp = x1 + ((s1 * 128 + t) << 6) + cb;
    const unsigned short* yf = ybuf + ((s1 * 128 + t) << 6) + cb;
    const unsigned short* yb = ybuf + (((s1 + 512) * 128 + t) << 6) + cb;
    float* tp = &T[f * 68 + cb];
    #pragma unroll
    for (int j = 0; j < 32; j += 4) {
      const float4 xv = *(const float4*)(xp + j);
      const uint2 yfv = *(const uint2*)(yf + j);
      const uint2 ybv = *(const uint2*)(yb + j);
      const float4 fv = *(const float4*)(fb + cb + j);
      tp[j + 0] = xv.x + bflo(yfv.x) + bflo(ybv.x) + fv.x;
      tp[j + 1] = xv.y + bfhi(yfv.x) + bfhi(ybv.x) + fv.y;
      tp[j + 2] = xv.z + bflo(yfv.y) + bflo(ybv.y) + fv.z;
      tp[j + 3] = xv.w + bfhi(yfv.y) + bfhi(ybv.y) + fv.w;
    }
  }
  __syncthreads();
  {
    const int c = tid >> 2, f0 = (tid & 3) << 5;
    float* op = out + (((size_t)(b * 64 + c) * 128 + t) << 7) + f0;
    #pragma unroll
    for (int j = 0; j < 32; j += 4) {
      float4 v;
      v.x = T[(f0 + j + 0) * 68 + c];
      v.y = T[(f0 + j + 1) * 68 + c];
      v.z = T[(f0 + j + 2) * 68 + c];
      v.w = T[(f0 + j + 3) * 68 + c];
      *(float4*)(op + j) = v;
    }
  }
}

extern "C" void kernel_launch(void* const* d_in, const int* in_sizes, int n_in,
                              void* d_out, int out_size, void* d_ws, size_t ws_size,
                              hipStream_t stream) {
  const float* x   = (const float*)d_in[0];
  const float* Wp  = (const float*)d_in[1];
  const float* cw  = (const float*)d_in[2];
  const float* cb  = (const float*)d_in[3];
  const float* dtb = (const float*)d_in[4];
  const float* Al  = (const float*)d_in[5];
  const float* Dp  = (const float*)d_in[6];
  const float* nw  = (const float*)d_in[7];
  const float* oW  = (const float*)d_in[8];
  const float* fW  = (const float*)d_in[9];
  const float* fb  = (const float*)d_in[10];
  const float* lnw = (const float*)d_in[11];
  const float* lnb = (const float*)d_in[12];

  float* ws = (float*)d_ws;
  float* Wc = ws;                                       // 32768 f32
  unsigned short* WpF = (unsigned short*)(ws + 32768);  // 102400 shorts
  unsigned short* WcF = (unsigned short*)(ws + 32768 + 51200); // 32768 shorts
  float* xbuf = ws + 32768 + 51200 + 16384;             // 4194304 f32
  unsigned short* y = (unsigned short*)(xbuf + 4194304); // 8388608 bf16

  precomp_wc<<<32, 256, 0, stream>>>(fW, oW, Wc);
  precomp_wcf<<<4, 256, 0, stream>>>(Wc, WcF);
  precomp_wpf<<<4, 256, 0, stream>>>(Wp, WpF);
  transp0<<<512, 256, 0, stream>>>(x, xbuf);
  mamba_dir<<<1024, 512, 0, stream>>>(xbuf, y, WpF, WcF, cw, cb, dtb, Al, Dp,
                                      nw, lnw, lnb, 0);
  combine0<<<512, 256, 0, stream>>>(x, y, fb, xbuf);
  mamba_dir<<<1024, 512, 0, stream>>>(xbuf, y, WpF, WcF, cw, cb, dtb, Al, Dp,
                                      nw, lnw, lnb, 1);
  combine1<<<512, 256, 0, stream>>>(xbuf, y, fb + 64, (float*)d_out);
}

// Round 7
// 400.131 us; speedup vs baseline: 1.2707x; 1.2707x over previous
//
#include <hip/hip_runtime.h>

#define EPSV 1e-5f

typedef short bf16x8 __attribute__((ext_vector_type(8)));
typedef float f32x4 __attribute__((ext_vector_type(4)));

__device__ __forceinline__ float sigmoidf_(float x) {
  return 1.f / (1.f + __expf(-x));
}
__device__ __forceinline__ unsigned short f2bf(float f) {
  unsigned int u = __float_as_uint(f);
  u += 0x7fffu + ((u >> 16) & 1u);
  return (unsigned short)(u >> 16);
}
__device__ __forceinline__ float bfu(unsigned short h) {
  union { unsigned int u; float f; } t; t.u = ((unsigned int)h) << 16; return t.f;
}
__device__ __forceinline__ float bflo(unsigned int u) {
  union { unsigned int x; float f; } t; t.x = u << 16; return t.f;
}
__device__ __forceinline__ float bfhi(unsigned int u) {
  union { unsigned int x; float f; } t; t.x = u & 0xffff0000u; return t.f;
}

// ---------------------------------------------------------------------------
// W_comb[i][m][k] = sum_j fusion_W[p][m][d*64+j] * out_W[i][j][k]
// ---------------------------------------------------------------------------
__global__ __launch_bounds__(256) void precomp_wc(
    const float* __restrict__ fW,   // (2,64,128)
    const float* __restrict__ oW,   // (4,64,128)
    float* __restrict__ Wc)         // (4,64,128)
{
  const int bi = blockIdx.x;
  const int i = bi >> 3, mg = bi & 7;
  const int m = (mg << 3) + (threadIdx.x >> 5);
  const int k0 = (threadIdx.x & 31) << 2;
  const int p = i >> 1, d = i & 1;
  const float* fr = fW + p * 8192 + m * 128 + d * 64;
  const float* orow = oW + i * 8192 + k0;
  float a0 = 0.f, a1 = 0.f, a2 = 0.f, a3 = 0.f;
  for (int j = 0; j < 64; ++j) {
    const float f = fr[j];
    const float4 o4 = *(const float4*)(orow + j * 128);
    a0 += f * o4.x; a1 += f * o4.y; a2 += f * o4.z; a3 += f * o4.w;
  }
  float* out = Wc + i * 8192 + m * 128 + k0;
  out[0] = a0; out[1] = a1; out[2] = a2; out[3] = a3;
}

// ---------------------------------------------------------------------------
// Wc -> bf16 MFMA B-fragment order: WcF[ip][tile(4)][h(4)][lane(64)][8]
// ---------------------------------------------------------------------------
__global__ __launch_bounds__(256) void precomp_wcf(
    const float* __restrict__ Wc, unsigned short* __restrict__ WcF)
{
  const int ip = blockIdx.x;
  const float* src = Wc + (size_t)ip * 8192;
  unsigned short* dst = WcF + (size_t)ip * 8192;
  for (int idx = threadIdx.x; idx < 8192; idx += 256) {
    const int tile = idx >> 11;
    const int h = (idx >> 9) & 3;
    const int lane = (idx >> 3) & 63;
    const int j = idx & 7;
    const int col = lane & 15, quad = lane >> 4;
    dst[idx] = f2bf(src[(tile * 16 + col) * 128 + h * 32 + quad * 8 + j]);
  }
}

// ---------------------------------------------------------------------------
// in_proj weights -> bf16 in MFMA B-fragment order (1KB coalesced per wave).
// ---------------------------------------------------------------------------
__global__ __launch_bounds__(256) void precomp_wpf(
    const float* __restrict__ Wp, unsigned short* __restrict__ WpF)
{
  const int ip = blockIdx.x;
  const float* src = Wp + (size_t)ip * 24704;
  unsigned short* dst = WpF + (size_t)ip * 25600;
  for (int idx = threadIdx.x; idx < 25600; idx += 256) {
    const int tile = idx >> 10;
    const int rem = idx & 1023;
    const int h = rem >> 9;
    const int lane = (rem >> 3) & 63;
    const int j = idx & 7;
    const int col = lane & 15, quad = lane >> 4;
    const int o = tile * 16 + col;
    const int k = h * 32 + quad * 8 + j;
    dst[idx] = (o < 386) ? f2bf(src[o * 64 + k]) : (unsigned short)0;
  }
}

// ---------------------------------------------------------------------------
// transp0: x0[b][t][f][c] = x[b][c][t][f]
// ---------------------------------------------------------------------------
__global__ __launch_bounds__(256) void transp0(
    const float* __restrict__ x, float* __restrict__ x0)
{
  __shared__ float T[64 * 132];
  const int tid = threadIdx.x, blk = blockIdx.x;
  const int b = blk >> 7, t = blk & 127;
  {
    const int c = tid >> 2, f0 = (tid & 3) << 5;
    const float* xp = x + (((size_t)(b * 64 + c) * 128 + t) << 7) + f0;
    float* tp = &T[c * 132 + f0];
    #pragma unroll
    for (int j = 0; j < 8; ++j)
      *(float4*)(tp + (j << 2)) = *(const float4*)(xp + (j << 2));
  }
  __syncthreads();
  {
    const int f = tid >> 1, cb = (tid & 1) << 5;
    float* op = x0 + (((size_t)(b * 128 + t) * 128 + f) << 6) + cb;
    #pragma unroll
    for (int j = 0; j < 32; j += 4) {
      float4 v;
      v.x = T[(cb + j + 0) * 132 + f];
      v.y = T[(cb + j + 1) * 132 + f];
      v.z = T[(cb + j + 2) * 132 + f];
      v.w = T[(cb + j + 3) * 132 + f];
      *(float4*)(op + j) = v;
    }
  }
}

// ---------------------------------------------------------------------------
// One block = one (sequence, direction). Chunked-SSD, 16-step chunks — the
// R1-measured schedule. Launch-bounds model (reconciled over R1/R3/R5/R6):
// arg2 = MIN WAVES PER EU (AMD semantics); caps TOTAL regs (VGPR+AGPR) at
// 512/arg2. This kernel carries ~64 AGPRs, so:
//   (512,4): total<=128 -> 4 waves/SIMD -> 2 blocks/CU (occ 40%, dur 134us)
//   (512,2)/(512,3): total ~140-150 -> 3 waves/SIMD -> 1 block/CU (occ 23%,
//   dur 172-187us) — occupancy loss dominates the spill savings.
// So keep (512,4) and instead ELIMINATE the spill by register diet: the
// loop-long-lived per-lane constants (cw4/cbias, lnw/lnb) are re-loaded
// inside their phases each chunk (28B/thread/chunk from L2-resident arrays).
// ---------------------------------------------------------------------------
__global__ __launch_bounds__(512, 4) void mamba_dir(
    const float* __restrict__ src,   // [seq][pos][c] f32 (x0 or x1)
    unsigned short* __restrict__ ybuf, // bf16 [dir][seq][pos][64]
    const unsigned short* __restrict__ WpF, // bf16 fragments (4,25600)
    const unsigned short* __restrict__ WcF, // bf16 fragments (4,8192)
    const float* __restrict__ cwA, const float* __restrict__ cbA,
    const float* __restrict__ dtbA, const float* __restrict__ AlA,
    const float* __restrict__ DpA, const float* __restrict__ nwA,
    const float* __restrict__ lnwA, const float* __restrict__ lnbA,
    int phase)
{
  __shared__ __align__(16) unsigned short sU[16 * 72];    // LN'd u (A-frag)
  __shared__ __align__(16) unsigned short sZb[16 * 136];  // z, then g
  __shared__ __align__(16) float sZx[16 * 260];           // raw xBC; y in cols 0-127
  __shared__ __align__(16) unsigned short sBC16[16 * 136];// bf16 B(0-63) C(64-127) row-major
  __shared__ __align__(16) unsigned short sXdT[128 * 40]; // bf16 x^T [c][t], t>=16 zero
  __shared__ __align__(16) unsigned short sXwT[128 * 40]; // bf16 (w_t*x)^T [c][t]
  __shared__ __align__(16) unsigned short sBT[64 * 40];   // bf16 B^T [n][t], t>=16 zero
  __shared__ __align__(16) unsigned short sSm[2 * 16 * 40]; // bf16 masked scores [h][t][s]
  __shared__ __align__(16) unsigned short sH[2 * 64 * 72];  // bf16 h snapshot [h][p][n]
  __shared__ float sMeta[16][2][4];                       // per (t,h): {L, dt, w, P}
  __shared__ float sDtRaw[16][2];

  const int tid = threadIdx.x;
  const int blk = blockIdx.x;
  const int seq = blk >> 1, dir = blk & 1;
  const int ip = (phase << 1) + dir;
  // uniform scalars (SGPR): no VGPR cost
  const float dtb0 = dtbA[ip * 2], dtb1 = dtbA[ip * 2 + 1];
  const float nA0 = -__expf(AlA[ip * 2]), nA1 = -__expf(AlA[ip * 2 + 1]);
  const float Dp0 = DpA[ip * 2], Dp1 = DpA[ip * 2 + 1];
  const int c256 = tid & 255;                 // conv channel
  const int lh = tid >> 8;                    // conv lt-half
  float ch0 = 0.f, ch1 = 0.f, ch2 = 0.f;      // conv carry (lh==0 only)

  const int wv = tid >> 6, lane = tid & 63;
  const int col = lane & 15, quad = lane >> 4;

  f32x4 hacc[8];                              // h state (waves 0-3): f32 accumulators
  #pragma unroll
  for (int i = 0; i < 8; ++i) hacc[i] = (f32x4){0.f, 0.f, 0.f, 0.f};

  // zero fragment arrays once: K-pad regions must stay 0; sH = initial state 0
  {
    unsigned int* z;
    z = (unsigned int*)sXdT; for (int i = tid; i < 2560; i += 512) z[i] = 0u;
    z = (unsigned int*)sXwT; for (int i = tid; i < 2560; i += 512) z[i] = 0u;
    z = (unsigned int*)sBT;  for (int i = tid; i < 1280; i += 512) z[i] = 0u;
    z = (unsigned int*)sSm;  for (int i = tid; i < 640;  i += 512) z[i] = 0u;
    z = (unsigned int*)sH;   for (int i = tid; i < 4608; i += 512) z[i] = 0u;
  }

  const unsigned short* wf = WpF + (size_t)ip * 25600;
  const unsigned short* wcf = WcF + (size_t)ip * 8192;
  const size_t sb = (size_t)seq << 13;
  const int pos = tid >> 6, lc = tid & 63;    // load/LN mapping

  // preload chunk 0 (2 floats/thread, coalesced)
  float vc0, vc1;
  {
    const int p0 = dir ? (127 - pos) : pos;
    const int p1 = dir ? (127 - (pos + 8)) : (pos + 8);
    vc0 = src[sb + (size_t)p0 * 64 + lc];
    vc1 = src[sb + (size_t)p1 * 64 + lc];
  }

  for (int ck = 0; ck < 8; ++ck) {
    // ---- prefetch next chunk ----
    float vn0 = 0.f, vn1 = 0.f;
    if (ck < 7) {
      const int st0 = ((ck + 1) << 4) + pos;
      const int p0 = dir ? (127 - st0) : st0;
      const int p1 = dir ? (127 - (st0 + 8)) : (st0 + 8);
      vn0 = src[sb + (size_t)p0 * 64 + lc];
      vn1 = src[sb + (size_t)p1 * 64 + lc];
    }
    // ---- 1+2. layernorm in registers (wave-shfl), write bf16 sU ----
    {
      // per-chunk reload (register diet): L2-resident, 8B/thread
      const int lnb_i = (phase << 6) + lc;
      const float lnw_v = lnwA[lnb_i], lnb_v = lnbA[lnb_i];
      #pragma unroll
      for (int half = 0; half < 2; ++half) {
        const float v = half ? vc1 : vc0;
        float sm = v, s2 = v * v;
        sm += __shfl_xor(sm, 1);  s2 += __shfl_xor(s2, 1);
        sm += __shfl_xor(sm, 2);  s2 += __shfl_xor(s2, 2);
        sm += __shfl_xor(sm, 4);  s2 += __shfl_xor(s2, 4);
        sm += __shfl_xor(sm, 8);  s2 += __shfl_xor(s2, 8);
        sm += __shfl_xor(sm, 16); s2 += __shfl_xor(s2, 16);
        sm += __shfl_xor(sm, 32); s2 += __shfl_xor(s2, 32);
        const float mean = sm * (1.f / 64.f);
        const float inv = rsqrtf(s2 * (1.f / 64.f) - mean * mean + EPSV);
        sU[(pos + half * 8) * 72 + lc] = f2bf((v - mean) * inv * lnw_v + lnb_v);
      }
    }
    __syncthreads();   // B1: sU ready; guards sZb/sZx vs prior step-7/3 reads
    // ---- 3. in_proj via MFMA; B fragments streamed from global/L2 ----
    {
      const int wave = tid >> 6;
      const bf16x8 a0 = *(const bf16x8*)(&sU[col * 72 + quad * 8]);
      const bf16x8 a1 = *(const bf16x8*)(&sU[col * 72 + quad * 8 + 32]);
      for (int tile = wave; tile < 25; tile += 8) {
        const unsigned short* wt = wf + (tile << 10) + (lane << 3);
        const bf16x8 b0 = *(const bf16x8*)(wt);
        const bf16x8 b1 = *(const bf16x8*)(wt + 512);
        f32x4 d = {0.f, 0.f, 0.f, 0.f};
        d = __builtin_amdgcn_mfma_f32_16x16x32_bf16(a0, b0, d, 0, 0, 0);
        d = __builtin_amdgcn_mfma_f32_16x16x32_bf16(a1, b1, d, 0, 0, 0);
        const int o = (tile << 4) + col;
        if (tile < 8) {               // z -> bf16
          #pragma unroll
          for (int r = 0; r < 4; ++r)
            sZb[(quad * 4 + r) * 136 + o] = f2bf(d[r]);
        } else if (tile < 24) {       // xBC -> f32
          #pragma unroll
          for (int r = 0; r < 4; ++r)
            sZx[(quad * 4 + r) * 260 + (o - 128)] = d[r];
        } else if (col < 2) {         // dt raw (o = 384,385)
          #pragma unroll
          for (int r = 0; r < 4; ++r)
            sDtRaw[quad * 4 + r][col] = d[r];
        }
      }
    }
    __syncthreads();   // B2
    // ---- 4. conv(4,causal)+silu -> bf16 fragment layouts; dt/L meta ----
    {
      const int c = c256;
      // per-chunk reload (register diet): 20B/thread, L2-resident
      const float4 cw4 = *(const float4*)(cwA + ip * 1024 + (c << 2));
      const float cbias = cbA[ip * 256 + c];
      float a0c, a1c, a2c;
      if (lh == 0) { a0c = ch0; a1c = ch1; a2c = ch2; }
      else {
        a0c = sZx[5 * 260 + c];
        a1c = sZx[6 * 260 + c];
        a2c = sZx[7 * 260 + c];
      }
      const int lt0 = lh << 3;
      unsigned int pkv[4];
      #pragma unroll
      for (int l = 0; l < 8; ++l) {
        const int lt = lt0 + l;
        const float a3 = sZx[lt * 260 + c];
        const float acc = cbias + a0c * cw4.x + a1c * cw4.y + a2c * cw4.z + a3 * cw4.w;
        const float sv = acc * sigmoidf_(acc);
        const unsigned int hv = (unsigned int)f2bf(sv);
        if (c >= 192)      sBC16[lt * 136 + 64 + (c - 192)] = (unsigned short)hv;
        else if (c >= 128) sBC16[lt * 136 + (c - 128)] = (unsigned short)hv;
        if (l & 1) pkv[l >> 1] |= hv << 16; else pkv[l >> 1] = hv;
        a0c = a1c; a1c = a2c; a2c = a3;
      }
      if (c < 128)
        *(uint4*)(&sXdT[c * 40 + lt0]) = make_uint4(pkv[0], pkv[1], pkv[2], pkv[3]);
      else if (c < 192)
        *(uint4*)(&sBT[(c - 128) * 40 + lt0]) = make_uint4(pkv[0], pkv[1], pkv[2], pkv[3]);
      if (lh == 0) {   // carry = raw xBC at lt 13,14,15
        ch0 = sZx[13 * 260 + c];
        ch1 = sZx[14 * 260 + c];
        ch2 = sZx[15 * 260 + c];
      }
      if (tid < 32) {
        const int lt = tid >> 1, hh = tid & 1;
        const float rawv = sDtRaw[lt][hh] + (hh ? dtb1 : dtb0);
        const float dtv = (rawv > 20.f) ? rawv : log1pf(__expf(rawv));
        float Lx = dtv * (hh ? nA1 : nA0);   // log dA_t
        #pragma unroll
        for (int d = 2; d < 32; d <<= 1) {   // inclusive prefix over lt (stride-2 lanes)
          const float tpv = __shfl_up(Lx, d);
          Lx += (tid >= d) ? tpv : 0.f;
        }
        const float Ltot = __shfl(Lx, 30 + hh);
        *(float4*)(&sMeta[lt][hh][0]) =
            make_float4(Lx, dtv, __expf(Ltot - Lx) * dtv, __expf(Lx));
      }
    }
    __syncthreads();   // B3
    // ---- 5a. G+mask (w0) | Xw fixup (w1-2) | y_inter (w4-7) ----
    f32x4 yD0, yD1;
    if (wv == 0) {
      const bf16x8 ca0 = *(const bf16x8*)(&sBC16[col * 136 + 64 + quad * 8]);
      const bf16x8 ca1 = *(const bf16x8*)(&sBC16[col * 136 + 96 + quad * 8]);
      const bf16x8 bb0 = *(const bf16x8*)(&sBC16[col * 136 + quad * 8]);
      const bf16x8 bb1 = *(const bf16x8*)(&sBC16[col * 136 + 32 + quad * 8]);
      f32x4 g = {0.f, 0.f, 0.f, 0.f};
      g = __builtin_amdgcn_mfma_f32_16x16x32_bf16(ca0, bb0, g, 0, 0, 0);
      g = __builtin_amdgcn_mfma_f32_16x16x32_bf16(ca1, bb1, g, 0, 0, 0);
      // D: row t = quad*4+r, col s = lane&15
      #pragma unroll
      for (int h = 0; h < 2; ++h) {
        const float Ls = sMeta[col][h][0];
        const float dts = sMeta[col][h][1];
        #pragma unroll
        for (int r = 0; r < 4; ++r) {
          const int t = quad * 4 + r;
          const float m = (col <= t) ? __expf(sMeta[t][h][0] - Ls) * dts : 0.f;
          sSm[(h * 16 + t) * 40 + col] = f2bf(g[r] * m);
        }
      }
    } else if (wv <= 2) {
      if (ck < 7) {     // Xw = w_t * x (feeds h-update only)
        const int p = ((wv - 1) << 6) + lane;
        const int hh = p >> 6;
        #pragma unroll
        for (int tp = 0; tp < 8; ++tp) {
          const unsigned int xr = *(const unsigned int*)(&sXdT[p * 40 + tp * 2]);
          const unsigned int lo = (unsigned int)f2bf(bflo(xr) * sMeta[tp * 2][hh][2]);
          const unsigned int hi = (unsigned int)f2bf(bfhi(xr) * sMeta[tp * 2 + 1][hh][2]);
          *(unsigned int*)(&sXwT[p * 40 + tp * 2]) = lo | (hi << 16);
        }
      }
    } else if (wv >= 4) {
      // y_inter[t,p] = P_t * sum_n C[t,n] h_prev[p,n]
      const int h = (wv - 4) >> 1, pt2 = (wv - 4) & 1;
      const bf16x8 ca0 = *(const bf16x8*)(&sBC16[col * 136 + 64 + quad * 8]);
      const bf16x8 ca1 = *(const bf16x8*)(&sBC16[col * 136 + 96 + quad * 8]);
      const unsigned short* hp0 = &sH[(h * 64 + pt2 * 32 + col) * 72];
      const unsigned short* hp1 = hp0 + 16 * 72;
      const bf16x8 h00 = *(const bf16x8*)(hp0 + quad * 8);
      const bf16x8 h01 = *(const bf16x8*)(hp0 + 32 + quad * 8);
      const bf16x8 h10 = *(const bf16x8*)(hp1 + quad * 8);
      const bf16x8 h11 = *(const bf16x8*)(hp1 + 32 + quad * 8);
      yD0 = (f32x4){0.f, 0.f, 0.f, 0.f};
      yD1 = (f32x4){0.f, 0.f, 0.f, 0.f};
      yD0 = __builtin_amdgcn_mfma_f32_16x16x32_bf16(ca0, h00, yD0, 0, 0, 0);
      yD0 = __builtin_amdgcn_mfma_f32_16x16x32_bf16(ca1, h01, yD0, 0, 0, 0);
      yD1 = __builtin_amdgcn_mfma_f32_16x16x32_bf16(ca0, h10, yD1, 0, 0, 0);
      yD1 = __builtin_amdgcn_mfma_f32_16x16x32_bf16(ca1, h11, yD1, 0, 0, 0);
      #pragma unroll
      for (int r = 0; r < 4; ++r) {
        const float Pv = sMeta[quad * 4 + r][h][3];
        yD0[r] *= Pv; yD1[r] *= Pv;
      }
    }
    __syncthreads();   // B4
    // ---- 5b. h-update (w0-3) | y_intra + D*x + y write (w4-7) ----
    if (wv < 4) {
      if (ck < 7) {
        const int h = wv >> 1, ph = wv & 1;
        const int pb = h * 64 + ph * 32;       // global x-channel base
        const float At = sMeta[15][h][3];      // exp(Ltot)
        const bf16x8 xa0 = *(const bf16x8*)(&sXwT[(pb + col) * 40 + quad * 8]);
        const bf16x8 xa1 = *(const bf16x8*)(&sXwT[(pb + 16 + col) * 40 + quad * 8]);
        #pragma unroll
        for (int nt = 0; nt < 4; ++nt) {
          const bf16x8 bbt = *(const bf16x8*)(&sBT[(nt * 16 + col) * 40 + quad * 8]);
          #pragma unroll
          for (int r = 0; r < 4; ++r) { hacc[nt][r] *= At; hacc[nt + 4][r] *= At; }
          hacc[nt]     = __builtin_amdgcn_mfma_f32_16x16x32_bf16(xa0, bbt, hacc[nt], 0, 0, 0);
          hacc[nt + 4] = __builtin_amdgcn_mfma_f32_16x16x32_bf16(xa1, bbt, hacc[nt + 4], 0, 0, 0);
        }
        // snapshot h -> sH bf16 for next chunk's y_inter
        #pragma unroll
        for (int nt = 0; nt < 4; ++nt) {
          #pragma unroll
          for (int r = 0; r < 4; ++r) {
            sH[(pb + quad * 4 + r) * 72 + nt * 16 + col] = f2bf(hacc[nt][r]);
            sH[(pb + 16 + quad * 4 + r) * 72 + nt * 16 + col] = f2bf(hacc[nt + 4][r]);
          }
        }
      }
    } else {
      const int h = (wv - 4) >> 1, pt2 = (wv - 4) & 1;
      const int cb0 = h * 64 + pt2 * 32;
      const float dp = h ? Dp1 : Dp0;
      const bf16x8 sa = *(const bf16x8*)(&sSm[(h * 16 + col) * 40 + quad * 8]);
      const bf16x8 xb0 = *(const bf16x8*)(&sXdT[(cb0 + col) * 40 + quad * 8]);
      const bf16x8 xb1 = *(const bf16x8*)(&sXdT[(cb0 + 16 + col) * 40 + quad * 8]);
      yD0 = __builtin_amdgcn_mfma_f32_16x16x32_bf16(sa, xb0, yD0, 0, 0, 0);
      yD1 = __builtin_amdgcn_mfma_f32_16x16x32_bf16(sa, xb1, yD1, 0, 0, 0);
      // + Dp * x (x[t,c] from transposed bf16, 4 consecutive t = one b64)
      const uint2 xw0 = *(const uint2*)(&sXdT[(cb0 + col) * 40 + quad * 4]);
      const uint2 xw1 = *(const uint2*)(&sXdT[(cb0 + 16 + col) * 40 + quad * 4]);
      yD0[0] += dp * bflo(xw0.x); yD0[1] += dp * bfhi(xw0.x);
      yD0[2] += dp * bflo(xw0.y); yD0[3] += dp * bfhi(xw0.y);
      yD1[0] += dp * bflo(xw1.x); yD1[1] += dp * bfhi(xw1.x);
      yD1[2] += dp * bflo(xw1.y); yD1[3] += dp * bfhi(xw1.y);
      #pragma unroll
      for (int r = 0; r < 4; ++r) {
        sZx[(quad * 4 + r) * 260 + cb0 + col] = yD0[r];
        sZx[(quad * 4 + r) * 260 + cb0 + 16 + col] = yD1[r];
      }
    }
    __syncthreads();   // B5
    // ---- 6. gate with silu(z) + rmsnorm -> bf16 g IN PLACE over z (sZb) ----
    {
      const int w = tid >> 6, kk = tid & 63, k0 = kk << 1;
      const float2 nw2 = *(const float2*)(nwA + ip * 128 + k0);
      #pragma unroll
      for (int sub = 0; sub < 2; ++sub) {
        const int lt = w + (sub << 3);
        const float2 yv = *(const float2*)(&sZx[lt * 260 + k0]);
        const unsigned int zp = *(const unsigned int*)(&sZb[lt * 136 + k0]);
        const float z0 = bflo(zp), z1 = bfhi(zp);
        const float g0 = yv.x * (z0 * sigmoidf_(z0));
        const float g1 = yv.y * (z1 * sigmoidf_(z1));
        float ssq = g0 * g0 + g1 * g1;
        ssq += __shfl_xor(ssq, 1);
        ssq += __shfl_xor(ssq, 2);
        ssq += __shfl_xor(ssq, 4);
        ssq += __shfl_xor(ssq, 8);
        ssq += __shfl_xor(ssq, 16);
        ssq += __shfl_xor(ssq, 32);
        const float sc = rsqrtf(ssq * (1.f / 128.f) + EPSV);
        const unsigned int lo = f2bf(g0 * sc * nw2.x);
        const unsigned int hi = f2bf(g1 * sc * nw2.y);
        *(unsigned int*)(&sZb[lt * 136 + k0]) = lo | (hi << 16);
      }
    }
    __syncthreads();   // B6
    // ---- 7. out-matmul via MFMA: g (16x128, A=sZb rows) @ WcF (4 m-tiles) ----
    {
      const int wave = tid >> 6;
      if (wave < 4) {
        const unsigned short* wt = wcf + (wave << 11);
        f32x4 d = {0.f, 0.f, 0.f, 0.f};
        #pragma unroll
        for (int h = 0; h < 4; ++h) {
          const bf16x8 a = *(const bf16x8*)(&sZb[col * 136 + (h << 5) + (quad << 3)]);
          const bf16x8 bb = *(const bf16x8*)(wt + (h << 9) + (lane << 3));
          d = __builtin_amdgcn_mfma_f32_16x16x32_bf16(a, bb, d, 0, 0, 0);
        }
        const size_t yb = ((size_t)(dir * 512 + seq) * 128) << 6;
        #pragma unroll
        for (int r = 0; r < 4; ++r) {
          const int pp = (quad << 2) + r;
          const int st = (ck << 4) + pp, rp = dir ? (127 - st) : st;
          ybuf[yb + ((size_t)rp << 6) + (wave << 4) + col] = f2bf(d[r]);
        }
      }
    }
    vc0 = vn0; vc1 = vn1;
  }
}

// ---------------------------------------------------------------------------
// combine0: x1[b][f][t][c] = x[b][c][t][f] + yf + yb + fb0[c]   (coalesced)
// ---------------------------------------------------------------------------
__global__ __launch_bounds__(256) void combine0(
    const float* __restrict__ x, const unsigned short* __restrict__ ybuf,
    const float* __restrict__ fb, float* __restrict__ x1)
{
  __shared__ float T[64 * 132];
  const int tid = threadIdx.x, blk = blockIdx.x;
  const int b = blk >> 7, t = blk & 127;
  {
    const int c = tid >> 2, f0 = (tid & 3) << 5;
    const float* xp = x + (((size_t)(b * 64 + c) * 128 + t) << 7) + f0;
    float* tp = &T[c * 132 + f0];
    #pragma unroll
    for (int j = 0; j < 8; ++j)
      *(float4*)(tp + (j << 2)) = *(const float4*)(xp + (j << 2));
  }
  __syncthreads();
  {
    const int f = tid >> 1, cb = (tid & 1) << 5;
    const size_t s0 = (size_t)b * 128 + t;
    const unsigned short* yf = ybuf + ((s0 * 128 + f) << 6) + cb;
    const unsigned short* yb = ybuf + (((s0 + 512) * 128 + f) << 6) + cb;
    float* op = x1 + (((size_t)(b * 128 + f) * 128 + t) << 6) + cb;
    #pragma unroll
    for (int j = 0; j < 32; j += 4) {
      float4 v;
      v.x = T[(cb + j + 0) * 132 + f] + bfu(yf[j + 0]) + bfu(yb[j + 0]) + fb[cb + j + 0];
      v.y = T[(cb + j + 1) * 132 + f] + bfu(yf[j + 1]) + bfu(yb[j + 1]) + fb[cb + j + 1];
      v.z = T[(cb + j + 2) * 132 + f] + bfu(yf[j + 2]) + bfu(yb[j + 2]) + fb[cb + j + 2];
      v.w = T[(cb + j + 3) * 132 + f] + bfu(yf[j + 3]) + bfu(yb[j + 3]) + fb[cb + j + 3];
      *(float4*)(op + j) = v;
    }
  }
}

// ---------------------------------------------------------------------------
// combine1: out[b][c][t][f] = x1[b][f][t][c] + yf + yb + fb1[c]  (coalesced)
// ---------------------------------------------------------------------------
__global__ __launch_bounds__(256) void combine1(
    const float* __restrict__ x1, const unsigned short* __restrict__ ybuf,
    const float* __restrict__ fb, float* __restrict__ out)
{
  __shared__ float T[128 * 68];
  const int tid = threadIdx.x, blk = blockIdx.x;
  const int b = blk >> 7, t = blk & 127;
  {
    const int f = tid >> 1, cb = (tid & 1) << 5;
    const size_t s1 = (size_t)b * 128 + f;
    const float* xp = x1 + ((s1 * 128 + t) << 6) + cb;
    const unsigned short* yf = ybuf + ((s1 * 128 + t) << 6) + cb;
    const unsigned short* yb = ybuf + (((s1 + 512) * 128 + t) << 6) + cb;
    float* tp = &T[f * 68 + cb];
    #pragma unroll
    for (int j = 0; j < 32; j += 4) {
      const float4 xv = *(const float4*)(xp + j);
      const uint2 yfv = *(const uint2*)(yf + j);
      const uint2 ybv = *(const uint2*)(yb + j);
      const float4 fv = *(const float4*)(fb + cb + j);
      tp[j + 0] = xv.x + bflo(yfv.x) + bflo(ybv.x) + fv.x;
      tp[j + 1] = xv.y + bfhi(yfv.x) + bfhi(ybv.x) + fv.y;
      tp[j + 2] = xv.z + bflo(yfv.y) + bflo(ybv.y) + fv.z;
      tp[j + 3] = xv.w + bfhi(yfv.y) + bfhi(ybv.y) + fv.w;
    }
  }
  __syncthreads();
  {
    const int c = tid >> 2, f0 = (tid & 3) << 5;
    float* op = out + (((size_t)(b * 64 + c) * 128 + t) << 7) + f0;
    #pragma unroll
    for (int j = 0; j < 32; j += 4) {
      float4 v;
      v.x = T[(f0 + j + 0) * 68 + c];
      v.y = T[(f0 + j + 1) * 68 + c];
      v.z = T[(f0 + j + 2) * 68 + c];
      v.w = T[(f0 + j + 3) * 68 + c];
      *(float4*)(op + j) = v;
    }
  }
}

extern "C" void kernel_launch(void* const* d_in, const int* in_sizes, int n_in,
                              void* d_out, int out_size, void* d_ws, size_t ws_size,
                              hipStream_t stream) {
  const float* x   = (const float*)d_in[0];
  const float* Wp  = (const float*)d_in[1];
  const float* cw  = (const float*)d_in[2];
  const float* cb  = (const float*)d_in[3];
  const float* dtb = (const float*)d_in[4];
  const float* Al  = (const float*)d_in[5];
  const float* Dp  = (const float*)d_in[6];
  const float* nw  = (const float*)d_in[7];
  const float* oW  = (const float*)d_in[8];
  const float* fW  = (const float*)d_in[9];
  const float* fb  = (const float*)d_in[10];
  const float* lnw = (const float*)d_in[11];
  const float* lnb = (const float*)d_in[12];

  float* ws = (float*)d_ws;
  float* Wc = ws;                                       // 32768 f32
  unsigned short* WpF = (unsigned short*)(ws + 32768);  // 102400 shorts
  unsigned short* WcF = (unsigned short*)(ws + 32768 + 51200); // 32768 shorts
  float* xbuf = ws + 32768 + 51200 + 16384;             // 4194304 f32
  unsigned short* y = (unsigned short*)(xbuf + 4194304); // 8388608 bf16

  precomp_wc<<<32, 256, 0, stream>>>(fW, oW, Wc);
  precomp_wcf<<<4, 256, 0, stream>>>(Wc, WcF);
  precomp_wpf<<<4, 256, 0, stream>>>(Wp, WpF);
  transp0<<<512, 256, 0, stream>>>(x, xbuf);
  mamba_dir<<<1024, 512, 0, stream>>>(xbuf, y, WpF, WcF, cw, cb, dtb, Al, Dp,
                                      nw, lnw, lnb, 0);
  combine0<<<512, 256, 0, stream>>>(x, y, fb, xbuf);
  mamba_dir<<<1024, 512, 0, stream>>>(xbuf, y, WpF, WcF, cw, cb, dtb, Al, Dp,
                                      nw, lnw, lnb, 1);
  combine1<<<512, 256, 0, stream>>>(xbuf, y, fb + 64, (float*)d_out);
}

// Round 8
// 382.223 us; speedup vs baseline: 1.3303x; 1.0469x over previous
//
#include <hip/hip_runtime.h>

#define EPSV 1e-5f

typedef short bf16x8 __attribute__((ext_vector_type(8)));
typedef float f32x4 __attribute__((ext_vector_type(4)));

__device__ __forceinline__ float sigmoidf_(float x) {
  return 1.f / (1.f + __expf(-x));
}
__device__ __forceinline__ unsigned short f2bf(float f) {
  unsigned int u = __float_as_uint(f);
  u += 0x7fffu + ((u >> 16) & 1u);
  return (unsigned short)(u >> 16);
}
__device__ __forceinline__ float bfu(unsigned short h) {
  union { unsigned int u; float f; } t; t.u = ((unsigned int)h) << 16; return t.f;
}
__device__ __forceinline__ float bflo(unsigned int u) {
  union { unsigned int x; float f; } t; t.x = u << 16; return t.f;
}
__device__ __forceinline__ float bfhi(unsigned int u) {
  union { unsigned int x; float f; } t; t.x = u & 0xffff0000u; return t.f;
}

// ---------------------------------------------------------------------------
// W_comb[i][m][k] = sum_j fusion_W[p][m][d*64+j] * out_W[i][j][k]
// ---------------------------------------------------------------------------
__global__ __launch_bounds__(256) void precomp_wc(
    const float* __restrict__ fW,   // (2,64,128)
    const float* __restrict__ oW,   // (4,64,128)
    float* __restrict__ Wc)         // (4,64,128)
{
  const int bi = blockIdx.x;
  const int i = bi >> 3, mg = bi & 7;
  const int m = (mg << 3) + (threadIdx.x >> 5);
  const int k0 = (threadIdx.x & 31) << 2;
  const int p = i >> 1, d = i & 1;
  const float* fr = fW + p * 8192 + m * 128 + d * 64;
  const float* orow = oW + i * 8192 + k0;
  float a0 = 0.f, a1 = 0.f, a2 = 0.f, a3 = 0.f;
  for (int j = 0; j < 64; ++j) {
    const float f = fr[j];
    const float4 o4 = *(const float4*)(orow + j * 128);
    a0 += f * o4.x; a1 += f * o4.y; a2 += f * o4.z; a3 += f * o4.w;
  }
  float* out = Wc + i * 8192 + m * 128 + k0;
  out[0] = a0; out[1] = a1; out[2] = a2; out[3] = a3;
}

// ---------------------------------------------------------------------------
// Wc -> bf16 MFMA B-fragment order: WcF[ip][tile(4)][h(4)][lane(64)][8]
// ---------------------------------------------------------------------------
__global__ __launch_bounds__(256) void precomp_wcf(
    const float* __restrict__ Wc, unsigned short* __restrict__ WcF)
{
  const int ip = blockIdx.x;
  const float* src = Wc + (size_t)ip * 8192;
  unsigned short* dst = WcF + (size_t)ip * 8192;
  for (int idx = threadIdx.x; idx < 8192; idx += 256) {
    const int tile = idx >> 11;
    const int h = (idx >> 9) & 3;
    const int lane = (idx >> 3) & 63;
    const int j = idx & 7;
    const int col = lane & 15, quad = lane >> 4;
    dst[idx] = f2bf(src[(tile * 16 + col) * 128 + h * 32 + quad * 8 + j]);
  }
}

// ---------------------------------------------------------------------------
// in_proj weights -> bf16 in MFMA B-fragment order (1KB coalesced per wave).
// ---------------------------------------------------------------------------
__global__ __launch_bounds__(256) void precomp_wpf(
    const float* __restrict__ Wp, unsigned short* __restrict__ WpF)
{
  const int ip = blockIdx.x;
  const float* src = Wp + (size_t)ip * 24704;
  unsigned short* dst = WpF + (size_t)ip * 25600;
  for (int idx = threadIdx.x; idx < 25600; idx += 256) {
    const int tile = idx >> 10;
    const int rem = idx & 1023;
    const int h = rem >> 9;
    const int lane = (rem >> 3) & 63;
    const int j = idx & 7;
    const int col = lane & 15, quad = lane >> 4;
    const int o = tile * 16 + col;
    const int k = h * 32 + quad * 8 + j;
    dst[idx] = (o < 386) ? f2bf(src[o * 64 + k]) : (unsigned short)0;
  }
}

// ---------------------------------------------------------------------------
// transp0: x0[b][t][f][c] = x[b][c][t][f]
// ---------------------------------------------------------------------------
__global__ __launch_bounds__(256) void transp0(
    const float* __restrict__ x, float* __restrict__ x0)
{
  __shared__ float T[64 * 132];
  const int tid = threadIdx.x, blk = blockIdx.x;
  const int b = blk >> 7, t = blk & 127;
  {
    const int c = tid >> 2, f0 = (tid & 3) << 5;
    const float* xp = x + (((size_t)(b * 64 + c) * 128 + t) << 7) + f0;
    float* tp = &T[c * 132 + f0];
    #pragma unroll
    for (int j = 0; j < 8; ++j)
      *(float4*)(tp + (j << 2)) = *(const float4*)(xp + (j << 2));
  }
  __syncthreads();
  {
    const int f = tid >> 1, cb = (tid & 1) << 5;
    float* op = x0 + (((size_t)(b * 128 + t) * 128 + f) << 6) + cb;
    #pragma unroll
    for (int j = 0; j < 32; j += 4) {
      float4 v;
      v.x = T[(cb + j + 0) * 132 + f];
      v.y = T[(cb + j + 1) * 132 + f];
      v.z = T[(cb + j + 2) * 132 + f];
      v.w = T[(cb + j + 3) * 132 + f];
      *(float4*)(op + j) = v;
    }
  }
}

// ---------------------------------------------------------------------------
// One block = one (sequence, direction). Chunked-SSD, 16-step chunks (R1
// schedule) at (512,4) [2 blocks/CU, occ 40% — measured optimal]. R1/R7
// spilled ~36 MB/dispatch under the 64-VGPR cap. This version shrinks the
// ARCHITECTURAL live state (compiler can't hoist it back):
//   - h-update on all 8 waves -> hacc[4] (16 regs, was 32 on w0-3)
//   - y_inter staged via LDS (dead sZx x-region) -> no f32x4x2 carried
//     across a barrier; y_intra consumes it as the MFMA C operand
// Cost: 7 barriers/chunk (was 6). Peak live ~55 < 64 -> no spill.
// ---------------------------------------------------------------------------
__global__ __launch_bounds__(512, 4) void mamba_dir(
    const float* __restrict__ src,   // [seq][pos][c] f32 (x0 or x1)
    unsigned short* __restrict__ ybuf, // bf16 [dir][seq][pos][64]
    const unsigned short* __restrict__ WpF, // bf16 fragments (4,25600)
    const unsigned short* __restrict__ WcF, // bf16 fragments (4,8192)
    const float* __restrict__ cwA, const float* __restrict__ cbA,
    const float* __restrict__ dtbA, const float* __restrict__ AlA,
    const float* __restrict__ DpA, const float* __restrict__ nwA,
    const float* __restrict__ lnwA, const float* __restrict__ lnbA,
    int phase)
{
  __shared__ __align__(16) unsigned short sU[16 * 72];    // LN'd u (A-frag)
  __shared__ __align__(16) unsigned short sZb[16 * 136];  // z, then g
  __shared__ __align__(16) float sZx[16 * 260];           // raw xBC; y in cols 0-127
  __shared__ __align__(16) unsigned short sBC16[16 * 136];// bf16 B(0-63) C(64-127) row-major
  __shared__ __align__(16) unsigned short sXdT[128 * 40]; // bf16 x^T [c][t], t>=16 zero
  __shared__ __align__(16) unsigned short sXwT[128 * 40]; // bf16 (w_t*x)^T [c][t]
  __shared__ __align__(16) unsigned short sBT[64 * 40];   // bf16 B^T [n][t], t>=16 zero
  __shared__ __align__(16) unsigned short sSm[2 * 16 * 40]; // bf16 masked scores [h][t][s]
  __shared__ __align__(16) unsigned short sH[2 * 64 * 72];  // bf16 h snapshot [h][p][n]
  __shared__ float sMeta[16][2][4];                       // per (t,h): {L, dt, w, P}
  __shared__ float sDtRaw[16][2];

  const int tid = threadIdx.x;
  const int blk = blockIdx.x;
  const int seq = blk >> 1, dir = blk & 1;
  const int ip = (phase << 1) + dir;
  // uniform scalars (SGPR): no VGPR cost
  const float dtb0 = dtbA[ip * 2], dtb1 = dtbA[ip * 2 + 1];
  const float nA0 = -__expf(AlA[ip * 2]), nA1 = -__expf(AlA[ip * 2 + 1]);
  const float Dp0 = DpA[ip * 2], Dp1 = DpA[ip * 2 + 1];
  const int c256 = tid & 255;                 // conv channel
  const int lh = tid >> 8;                    // conv lt-half
  float ch0 = 0.f, ch1 = 0.f, ch2 = 0.f;      // conv carry (lh==0 only)

  const int wv = tid >> 6, lane = tid & 63;
  const int col = lane & 15, quad = lane >> 4;

  f32x4 hacc[4];   // h state: ALL 8 waves, 16 p-channels each (16 regs)
  #pragma unroll
  for (int i = 0; i < 4; ++i) hacc[i] = (f32x4){0.f, 0.f, 0.f, 0.f};

  // zero fragment arrays once: K-pad regions must stay 0; sH = initial state 0
  {
    unsigned int* z;
    z = (unsigned int*)sXdT; for (int i = tid; i < 2560; i += 512) z[i] = 0u;
    z = (unsigned int*)sXwT; for (int i = tid; i < 2560; i += 512) z[i] = 0u;
    z = (unsigned int*)sBT;  for (int i = tid; i < 1280; i += 512) z[i] = 0u;
    z = (unsigned int*)sSm;  for (int i = tid; i < 640;  i += 512) z[i] = 0u;
    z = (unsigned int*)sH;   for (int i = tid; i < 4608; i += 512) z[i] = 0u;
  }

  const unsigned short* wf = WpF + (size_t)ip * 25600;
  const unsigned short* wcf = WcF + (size_t)ip * 8192;
  const size_t sb = (size_t)seq << 13;
  const int pos = tid >> 6, lc = tid & 63;    // load/LN mapping

  // preload chunk 0 (2 floats/thread, coalesced)
  float vc0, vc1;
  {
    const int p0 = dir ? (127 - pos) : pos;
    const int p1 = dir ? (127 - (pos + 8)) : (pos + 8);
    vc0 = src[sb + (size_t)p0 * 64 + lc];
    vc1 = src[sb + (size_t)p1 * 64 + lc];
  }

  for (int ck = 0; ck < 8; ++ck) {
    // ---- prefetch next chunk ----
    float vn0 = 0.f, vn1 = 0.f;
    if (ck < 7) {
      const int st0 = ((ck + 1) << 4) + pos;
      const int p0 = dir ? (127 - st0) : st0;
      const int p1 = dir ? (127 - (st0 + 8)) : (st0 + 8);
      vn0 = src[sb + (size_t)p0 * 64 + lc];
      vn1 = src[sb + (size_t)p1 * 64 + lc];
    }
    // ---- P1: layernorm in registers (wave-shfl), write bf16 sU ----
    {
      const int lnb_i = (phase << 6) + lc;
      const float lnw_v = lnwA[lnb_i], lnb_v = lnbA[lnb_i];
      #pragma unroll
      for (int half = 0; half < 2; ++half) {
        const float v = half ? vc1 : vc0;
        float sm = v, s2 = v * v;
        sm += __shfl_xor(sm, 1);  s2 += __shfl_xor(s2, 1);
        sm += __shfl_xor(sm, 2);  s2 += __shfl_xor(s2, 2);
        sm += __shfl_xor(sm, 4);  s2 += __shfl_xor(s2, 4);
        sm += __shfl_xor(sm, 8);  s2 += __shfl_xor(s2, 8);
        sm += __shfl_xor(sm, 16); s2 += __shfl_xor(s2, 16);
        sm += __shfl_xor(sm, 32); s2 += __shfl_xor(s2, 32);
        const float mean = sm * (1.f / 64.f);
        const float inv = rsqrtf(s2 * (1.f / 64.f) - mean * mean + EPSV);
        sU[(pos + half * 8) * 72 + lc] = f2bf((v - mean) * inv * lnw_v + lnb_v);
      }
    }
    __syncthreads();   // B1
    // ---- P2: in_proj via MFMA; B fragments streamed from global/L2 ----
    {
      const bf16x8 a0 = *(const bf16x8*)(&sU[col * 72 + quad * 8]);
      const bf16x8 a1 = *(const bf16x8*)(&sU[col * 72 + quad * 8 + 32]);
      for (int tile = wv; tile < 25; tile += 8) {
        const unsigned short* wt = wf + (tile << 10) + (lane << 3);
        const bf16x8 b0 = *(const bf16x8*)(wt);
        const bf16x8 b1 = *(const bf16x8*)(wt + 512);
        f32x4 d = {0.f, 0.f, 0.f, 0.f};
        d = __builtin_amdgcn_mfma_f32_16x16x32_bf16(a0, b0, d, 0, 0, 0);
        d = __builtin_amdgcn_mfma_f32_16x16x32_bf16(a1, b1, d, 0, 0, 0);
        const int o = (tile << 4) + col;
        if (tile < 8) {               // z -> bf16
          #pragma unroll
          for (int r = 0; r < 4; ++r)
            sZb[(quad * 4 + r) * 136 + o] = f2bf(d[r]);
        } else if (tile < 24) {       // xBC -> f32
          #pragma unroll
          for (int r = 0; r < 4; ++r)
            sZx[(quad * 4 + r) * 260 + (o - 128)] = d[r];
        } else if (col < 2) {         // dt raw (o = 384,385)
          #pragma unroll
          for (int r = 0; r < 4; ++r)
            sDtRaw[quad * 4 + r][col] = d[r];
        }
      }
    }
    __syncthreads();   // B2
    // ---- P3: conv(4,causal)+silu -> bf16 fragment layouts; dt/L meta ----
    {
      const int c = c256;
      const float4 cw4 = *(const float4*)(cwA + ip * 1024 + (c << 2));
      const float cbias = cbA[ip * 256 + c];
      float a0c, a1c, a2c;
      if (lh == 0) { a0c = ch0; a1c = ch1; a2c = ch2; }
      else {
        a0c = sZx[5 * 260 + c];
        a1c = sZx[6 * 260 + c];
        a2c = sZx[7 * 260 + c];
      }
      const int lt0 = lh << 3;
      unsigned int pkv[4];
      #pragma unroll
      for (int l = 0; l < 8; ++l) {
        const int lt = lt0 + l;
        const float a3 = sZx[lt * 260 + c];
        const float acc = cbias + a0c * cw4.x + a1c * cw4.y + a2c * cw4.z + a3 * cw4.w;
        const float sv = acc * sigmoidf_(acc);
        const unsigned int hv = (unsigned int)f2bf(sv);
        if (c >= 192)      sBC16[lt * 136 + 64 + (c - 192)] = (unsigned short)hv;
        else if (c >= 128) sBC16[lt * 136 + (c - 128)] = (unsigned short)hv;
        if (l & 1) pkv[l >> 1] |= hv << 16; else pkv[l >> 1] = hv;
        a0c = a1c; a1c = a2c; a2c = a3;
      }
      if (c < 128)
        *(uint4*)(&sXdT[c * 40 + lt0]) = make_uint4(pkv[0], pkv[1], pkv[2], pkv[3]);
      else if (c < 192)
        *(uint4*)(&sBT[(c - 128) * 40 + lt0]) = make_uint4(pkv[0], pkv[1], pkv[2], pkv[3]);
      if (lh == 0) {   // carry = raw xBC at lt 13,14,15
        ch0 = sZx[13 * 260 + c];
        ch1 = sZx[14 * 260 + c];
        ch2 = sZx[15 * 260 + c];
      }
      if (tid < 32) {
        const int lt = tid >> 1, hh = tid & 1;
        const float rawv = sDtRaw[lt][hh] + (hh ? dtb1 : dtb0);
        const float dtv = (rawv > 20.f) ? rawv : log1pf(__expf(rawv));
        float Lx = dtv * (hh ? nA1 : nA0);   // log dA_t
        #pragma unroll
        for (int d = 2; d < 32; d <<= 1) {   // inclusive prefix over lt (stride-2 lanes)
          const float tpv = __shfl_up(Lx, d);
          Lx += (tid >= d) ? tpv : 0.f;
        }
        const float Ltot = __shfl(Lx, 30 + hh);
        *(float4*)(&sMeta[lt][hh][0]) =
            make_float4(Lx, dtv, __expf(Ltot - Lx) * dtv, __expf(Lx));
      }
    }
    __syncthreads();   // B3
    // ---- P5a: G+mask (w0) | Xw fixup (w1-2) | y_inter -> sZx (w4-7) ----
    if (wv == 0) {
      const bf16x8 ca0 = *(const bf16x8*)(&sBC16[col * 136 + 64 + quad * 8]);
      const bf16x8 ca1 = *(const bf16x8*)(&sBC16[col * 136 + 96 + quad * 8]);
      const bf16x8 bb0 = *(const bf16x8*)(&sBC16[col * 136 + quad * 8]);
      const bf16x8 bb1 = *(const bf16x8*)(&sBC16[col * 136 + 32 + quad * 8]);
      f32x4 g = {0.f, 0.f, 0.f, 0.f};
      g = __builtin_amdgcn_mfma_f32_16x16x32_bf16(ca0, bb0, g, 0, 0, 0);
      g = __builtin_amdgcn_mfma_f32_16x16x32_bf16(ca1, bb1, g, 0, 0, 0);
      // D: row t = quad*4+r, col s = lane&15
      #pragma unroll
      for (int h = 0; h < 2; ++h) {
        const float Ls = sMeta[col][h][0];
        const float dts = sMeta[col][h][1];
        #pragma unroll
        for (int r = 0; r < 4; ++r) {
          const int t = quad * 4 + r;
          const float m = (col <= t) ? __expf(sMeta[t][h][0] - Ls) * dts : 0.f;
          sSm[(h * 16 + t) * 40 + col] = f2bf(g[r] * m);
        }
      }
    } else if (wv <= 2) {
      if (ck < 7) {     // Xw = w_t * x (feeds h-update only)
        const int p = ((wv - 1) << 6) + lane;
        const int hh = p >> 6;
        #pragma unroll
        for (int tp = 0; tp < 8; ++tp) {
          const unsigned int xr = *(const unsigned int*)(&sXdT[p * 40 + tp * 2]);
          const unsigned int lo = (unsigned int)f2bf(bflo(xr) * sMeta[tp * 2][hh][2]);
          const unsigned int hi = (unsigned int)f2bf(bfhi(xr) * sMeta[tp * 2 + 1][hh][2]);
          *(unsigned int*)(&sXwT[p * 40 + tp * 2]) = lo | (hi << 16);
        }
      }
    } else if (wv >= 4) {
      // y_inter[t,c] = P_t * sum_n C[t,n] h_prev[c,n]  -> staged into sZx
      const int h = (wv - 4) >> 1, pt2 = (wv - 4) & 1;
      const int cb0 = h * 64 + pt2 * 32;
      if (ck) {
        const bf16x8 ca0 = *(const bf16x8*)(&sBC16[col * 136 + 64 + quad * 8]);
        const bf16x8 ca1 = *(const bf16x8*)(&sBC16[col * 136 + 96 + quad * 8]);
        #pragma unroll
        for (int half = 0; half < 2; ++half) {
          const unsigned short* hp = &sH[(cb0 + half * 16 + col) * 72];
          const bf16x8 h0 = *(const bf16x8*)(hp + quad * 8);
          const bf16x8 h1 = *(const bf16x8*)(hp + 32 + quad * 8);
          f32x4 d = {0.f, 0.f, 0.f, 0.f};
          d = __builtin_amdgcn_mfma_f32_16x16x32_bf16(ca0, h0, d, 0, 0, 0);
          d = __builtin_amdgcn_mfma_f32_16x16x32_bf16(ca1, h1, d, 0, 0, 0);
          #pragma unroll
          for (int r = 0; r < 4; ++r)
            sZx[(quad * 4 + r) * 260 + cb0 + half * 16 + col] =
                d[r] * sMeta[quad * 4 + r][h][3];
        }
      } else {
        #pragma unroll
        for (int r = 0; r < 4; ++r) {
          sZx[(quad * 4 + r) * 260 + cb0 + col] = 0.f;
          sZx[(quad * 4 + r) * 260 + cb0 + 16 + col] = 0.f;
        }
      }
    }
    __syncthreads();   // B4
    // ---- P5b: h-update + snapshot on ALL 8 waves (16 p-channels each) ----
    if (ck < 7) {
      const int h = wv >> 2;
      const int pb = wv << 4;
      const float At = sMeta[15][h][3];      // exp(Ltot)
      const bf16x8 xa = *(const bf16x8*)(&sXwT[(pb + col) * 40 + quad * 8]);
      #pragma unroll
      for (int nt = 0; nt < 4; ++nt) {
        const bf16x8 bbt = *(const bf16x8*)(&sBT[(nt * 16 + col) * 40 + quad * 8]);
        #pragma unroll
        for (int r = 0; r < 4; ++r) hacc[nt][r] *= At;
        hacc[nt] = __builtin_amdgcn_mfma_f32_16x16x32_bf16(xa, bbt, hacc[nt], 0, 0, 0);
      }
      #pragma unroll
      for (int nt = 0; nt < 4; ++nt) {
        #pragma unroll
        for (int r = 0; r < 4; ++r)
          sH[(pb + quad * 4 + r) * 72 + nt * 16 + col] = f2bf(hacc[nt][r]);
      }
    }
    __syncthreads();   // B5
    // ---- P5c: y_intra (C = staged y_inter) + D*x on ALL 8 waves ----
    {
      const int h = wv >> 2;
      const int c = (wv << 4) + col;
      const float dp = h ? Dp1 : Dp0;
      const bf16x8 sa = *(const bf16x8*)(&sSm[(h * 16 + col) * 40 + quad * 8]);
      const bf16x8 xb = *(const bf16x8*)(&sXdT[c * 40 + quad * 8]);
      f32x4 cin;
      #pragma unroll
      for (int r = 0; r < 4; ++r) cin[r] = sZx[(quad * 4 + r) * 260 + c];
      f32x4 yD = __builtin_amdgcn_mfma_f32_16x16x32_bf16(sa, xb, cin, 0, 0, 0);
      const uint2 xw = *(const uint2*)(&sXdT[c * 40 + quad * 4]);
      yD[0] += dp * bflo(xw.x); yD[1] += dp * bfhi(xw.x);
      yD[2] += dp * bflo(xw.y); yD[3] += dp * bfhi(xw.y);
      #pragma unroll
      for (int r = 0; r < 4; ++r)
        sZx[(quad * 4 + r) * 260 + c] = yD[r];
    }
    __syncthreads();   // B6
    // ---- P6: gate with silu(z) + rmsnorm -> bf16 g IN PLACE over z (sZb) ----
    {
      const int k0 = lc << 1;
      const float2 nw2 = *(const float2*)(nwA + ip * 128 + k0);
      #pragma unroll
      for (int sub = 0; sub < 2; ++sub) {
        const int lt = wv + (sub << 3);
        const float2 yv = *(const float2*)(&sZx[lt * 260 + k0]);
        const unsigned int zp = *(const unsigned int*)(&sZb[lt * 136 + k0]);
        const float z0 = bflo(zp), z1 = bfhi(zp);
        const float g0 = yv.x * (z0 * sigmoidf_(z0));
        const float g1 = yv.y * (z1 * sigmoidf_(z1));
        float ssq = g0 * g0 + g1 * g1;
        ssq += __shfl_xor(ssq, 1);
        ssq += __shfl_xor(ssq, 2);
        ssq += __shfl_xor(ssq, 4);
        ssq += __shfl_xor(ssq, 8);
        ssq += __shfl_xor(ssq, 16);
        ssq += __shfl_xor(ssq, 32);
        const float sc = rsqrtf(ssq * (1.f / 128.f) + EPSV);
        const unsigned int lo = f2bf(g0 * sc * nw2.x);
        const unsigned int hi = f2bf(g1 * sc * nw2.y);
        *(unsigned int*)(&sZb[lt * 136 + k0]) = lo | (hi << 16);
      }
    }
    __syncthreads();   // B7
    // ---- P7: out-matmul via MFMA: g (16x128, A=sZb rows) @ WcF (4 m-tiles) ----
    {
      if (wv < 4) {
        const unsigned short* wt = wcf + (wv << 11);
        f32x4 d = {0.f, 0.f, 0.f, 0.f};
        #pragma unroll
        for (int h = 0; h < 4; ++h) {
          const bf16x8 a = *(const bf16x8*)(&sZb[col * 136 + (h << 5) + (quad << 3)]);
          const bf16x8 bb = *(const bf16x8*)(wt + (h << 9) + (lane << 3));
          d = __builtin_amdgcn_mfma_f32_16x16x32_bf16(a, bb, d, 0, 0, 0);
        }
        const size_t yb = ((size_t)(dir * 512 + seq) * 128) << 6;
        #pragma unroll
        for (int r = 0; r < 4; ++r) {
          const int pp = (quad << 2) + r;
          const int st = (ck << 4) + pp, rp = dir ? (127 - st) : st;
          ybuf[yb + ((size_t)rp << 6) + (wv << 4) + col] = f2bf(d[r]);
        }
      }
    }
    vc0 = vn0; vc1 = vn1;
  }
}

// ---------------------------------------------------------------------------
// combine0: x1[b][f][t][c] = x[b][c][t][f] + yf + yb + fb0[c]   (coalesced)
// ---------------------------------------------------------------------------
__global__ __launch_bounds__(256) void combine0(
    const float* __restrict__ x, const unsigned short* __restrict__ ybuf,
    const float* __restrict__ fb, float* __restrict__ x1)
{
  __shared__ float T[64 * 132];
  const int tid = threadIdx.x, blk = blockIdx.x;
  const int b = blk >> 7, t = blk & 127;
  {
    const int c = tid >> 2, f0 = (tid & 3) << 5;
    const float* xp = x + (((size_t)(b * 64 + c) * 128 + t) << 7) + f0;
    float* tp = &T[c * 132 + f0];
    #pragma unroll
    for (int j = 0; j < 8; ++j)
      *(float4*)(tp + (j << 2)) = *(const float4*)(xp + (j << 2));
  }
  __syncthreads();
  {
    const int f = tid >> 1, cb = (tid & 1) << 5;
    const size_t s0 = (size_t)b * 128 + t;
    const unsigned short* yf = ybuf + ((s0 * 128 + f) << 6) + cb;
    const unsigned short* yb = ybuf + (((s0 + 512) * 128 + f) << 6) + cb;
    float* op = x1 + (((size_t)(b * 128 + f) * 128 + t) << 6) + cb;
    #pragma unroll
    for (int j = 0; j < 32; j += 4) {
      float4 v;
      v.x = T[(cb + j + 0) * 132 + f] + bfu(yf[j + 0]) + bfu(yb[j + 0]) + fb[cb + j + 0];
      v.y = T[(cb + j + 1) * 132 + f] + bfu(yf[j + 1]) + bfu(yb[j + 1]) + fb[cb + j + 1];
      v.z = T[(cb + j + 2) * 132 + f] + bfu(yf[j + 2]) + bfu(yb[j + 2]) + fb[cb + j + 2];
      v.w = T[(cb + j + 3) * 132 + f] + bfu(yf[j + 3]) + bfu(yb[j + 3]) + fb[cb + j + 3];
      *(float4*)(op + j) = v;
    }
  }
}

// ---------------------------------------------------------------------------
// combine1: out[b][c][t][f] = x1[b][f][t][c] + yf + yb + fb1[c]  (coalesced)
// ---------------------------------------------------------------------------
__global__ __launch_bounds__(256) void combine1(
    const float* __restrict__ x1, const unsigned short* __restrict__ ybuf,
    const float* __restrict__ fb, float* __restrict__ out)
{
  __shared__ float T[128 * 68];
  const int tid = threadIdx.x, blk = blockIdx.x;
  const int b = blk >> 7, t = blk & 127;
  {
    const int f = tid >> 1, cb = (tid & 1) << 5;
    const size_t s1 = (size_t)b * 128 + f;
    const float* xp = x1 + ((s1 * 128 + t) << 6) + cb;
    const unsigned short* yf = ybuf + ((s1 * 128 + t) << 6) + cb;
    const unsigned short* yb = ybuf + (((s1 + 512) * 128 + t) << 6) + cb;
    float* tp = &T[f * 68 + cb];
    #pragma unroll
    for (int j = 0; j < 32; j += 4) {
      const float4 xv = *(const float4*)(xp + j);
      const uint2 yfv = *(const uint2*)(yf + j);
      const uint2 ybv = *(const uint2*)(yb + j);
      const float4 fv = *(const float4*)(fb + cb + j);
      tp[j + 0] = xv.x + bflo(yfv.x) + bflo(ybv.x) + fv.x;
      tp[j + 1] = xv.y + bfhi(yfv.x) + bfhi(ybv.x) + fv.y;
      tp[j + 2] = xv.z + bflo(yfv.y) + bflo(ybv.y) + fv.z;
      tp[j + 3] = xv.w + bfhi(yfv.y) + bfhi(ybv.y) + fv.w;
    }
  }
  __syncthreads();
  {
    const int c = tid >> 2, f0 = (tid & 3) << 5;
    float* op = out + (((size_t)(b * 64 + c) * 128 + t) << 7) + f0;
    #pragma unroll
    for (int j = 0; j < 32; j += 4) {
      float4 v;
      v.x = T[(f0 + j + 0) * 68 + c];
      v.y = T[(f0 + j + 1) * 68 + c];
      v.z = T[(f0 + j + 2) * 68 + c];
      v.w = T[(f0 + j + 3) * 68 + c];
      *(float4*)(op + j) = v;
    }
  }
}

extern "C" void kernel_launch(void* const* d_in, const int* in_sizes, int n_in,
                              void* d_out, int out_size, void* d_ws, size_t ws_size,
                              hipStream_t stream) {
  const float* x   = (const float*)d_in[0];
  const float* Wp  = (const float*)d_in[1];
  const float* cw  = (const float*)d_in[2];
  const float* cb  = (const float*)d_in[3];
  const float* dtb = (const float*)d_in[4];
  const float* Al  = (const float*)d_in[5];
  const float* Dp  = (const float*)d_in[6];
  const float* nw  = (const float*)d_in[7];
  const float* oW  = (const float*)d_in[8];
  const float* fW  = (const float*)d_in[9];
  const float* fb  = (const float*)d_in[10];
  const float* lnw = (const float*)d_in[11];
  const float* lnb = (const float*)d_in[12];

  float* ws = (float*)d_ws;
  float* Wc = ws;                                       // 32768 f32
  unsigned short* WpF = (unsigned short*)(ws + 32768);  // 102400 shorts
  unsigned short* WcF = (unsigned short*)(ws + 32768 + 51200); // 32768 shorts
  float* xbuf = ws + 32768 + 51200 + 16384;             // 4194304 f32
  unsigned short* y = (unsigned short*)(xbuf + 4194304); // 8388608 bf16

  precomp_wc<<<32, 256, 0, stream>>>(fW, oW, Wc);
  precomp_wcf<<<4, 256, 0, stream>>>(Wc, WcF);
  precomp_wpf<<<4, 256, 0, stream>>>(Wp, WpF);
  transp0<<<512, 256, 0, stream>>>(x, xbuf);
  mamba_dir<<<1024, 512, 0, stream>>>(xbuf, y, WpF, WcF, cw, cb, dtb, Al, Dp,
                                      nw, lnw, lnb, 0);
  combine0<<<512, 256, 0, stream>>>(x, y, fb, xbuf);
  mamba_dir<<<1024, 512, 0, stream>>>(xbuf, y, WpF, WcF, cw, cb, dtb, Al, Dp,
                                      nw, lnw, lnb, 1);
  combine1<<<512, 256, 0, stream>>>(xbuf, y, fb + 64, (float*)d_out);
}

// Round 10
// 381.193 us; speedup vs baseline: 1.3339x; 1.0027x over previous
//
#include <hip/hip_runtime.h>

#define EPSV 1e-5f

typedef short bf16x8 __attribute__((ext_vector_type(8)));
typedef float f32x4 __attribute__((ext_vector_type(4)));

__device__ __forceinline__ float sigmoidf_(float x) {
  return 1.f / (1.f + __expf(-x));
}
__device__ __forceinline__ unsigned short f2bf(float f) {
  unsigned int u = __float_as_uint(f);
  u += 0x7fffu + ((u >> 16) & 1u);
  return (unsigned short)(u >> 16);
}
__device__ __forceinline__ float bfu(unsigned short h) {
  union { unsigned int u; float f; } t; t.u = ((unsigned int)h) << 16; return t.f;
}
__device__ __forceinline__ float bflo(unsigned int u) {
  union { unsigned int x; float f; } t; t.x = u << 16; return t.f;
}
__device__ __forceinline__ float bfhi(unsigned int u) {
  union { unsigned int x; float f; } t; t.x = u & 0xffff0000u; return t.f;
}

// ---------------------------------------------------------------------------
// W_comb[i][m][k] = sum_j fusion_W[p][m][d*64+j] * out_W[i][j][k]
// ---------------------------------------------------------------------------
__global__ __launch_bounds__(256) void precomp_wc(
    const float* __restrict__ fW,   // (2,64,128)
    const float* __restrict__ oW,   // (4,64,128)
    float* __restrict__ Wc)         // (4,64,128)
{
  const int bi = blockIdx.x;
  const int i = bi >> 3, mg = bi & 7;
  const int m = (mg << 3) + (threadIdx.x >> 5);
  const int k0 = (threadIdx.x & 31) << 2;
  const int p = i >> 1, d = i & 1;
  const float* fr = fW + p * 8192 + m * 128 + d * 64;
  const float* orow = oW + i * 8192 + k0;
  float a0 = 0.f, a1 = 0.f, a2 = 0.f, a3 = 0.f;
  for (int j = 0; j < 64; ++j) {
    const float f = fr[j];
    const float4 o4 = *(const float4*)(orow + j * 128);
    a0 += f * o4.x; a1 += f * o4.y; a2 += f * o4.z; a3 += f * o4.w;
  }
  float* out = Wc + i * 8192 + m * 128 + k0;
  out[0] = a0; out[1] = a1; out[2] = a2; out[3] = a3;
}

// ---------------------------------------------------------------------------
// Wc -> bf16 MFMA B-fragment order: WcF[ip][tile(4)][h(4)][lane(64)][8]
// ---------------------------------------------------------------------------
__global__ __launch_bounds__(256) void precomp_wcf(
    const float* __restrict__ Wc, unsigned short* __restrict__ WcF)
{
  const int ip = blockIdx.x;
  const float* src = Wc + (size_t)ip * 8192;
  unsigned short* dst = WcF + (size_t)ip * 8192;
  for (int idx = threadIdx.x; idx < 8192; idx += 256) {
    const int tile = idx >> 11;
    const int h = (idx >> 9) & 3;
    const int lane = (idx >> 3) & 63;
    const int j = idx & 7;
    const int col = lane & 15, quad = lane >> 4;
    dst[idx] = f2bf(src[(tile * 16 + col) * 128 + h * 32 + quad * 8 + j]);
  }
}

// ---------------------------------------------------------------------------
// in_proj weights -> bf16 in MFMA B-fragment order (1KB coalesced per wave).
// ---------------------------------------------------------------------------
__global__ __launch_bounds__(256) void precomp_wpf(
    const float* __restrict__ Wp, unsigned short* __restrict__ WpF)
{
  const int ip = blockIdx.x;
  const float* src = Wp + (size_t)ip * 24704;
  unsigned short* dst = WpF + (size_t)ip * 25600;
  for (int idx = threadIdx.x; idx < 25600; idx += 256) {
    const int tile = idx >> 10;
    const int rem = idx & 1023;
    const int h = rem >> 9;
    const int lane = (rem >> 3) & 63;
    const int j = idx & 7;
    const int col = lane & 15, quad = lane >> 4;
    const int o = tile * 16 + col;
    const int k = h * 32 + quad * 8 + j;
    dst[idx] = (o < 386) ? f2bf(src[o * 64 + k]) : (unsigned short)0;
  }
}

// ---------------------------------------------------------------------------
// transp0: x0[b][t][f][c] = x[b][c][t][f]
// ---------------------------------------------------------------------------
__global__ __launch_bounds__(256) void transp0(
    const float* __restrict__ x, float* __restrict__ x0)
{
  __shared__ float T[64 * 132];
  const int tid = threadIdx.x, blk = blockIdx.x;
  const int b = blk >> 7, t = blk & 127;
  {
    const int c = tid >> 2, f0 = (tid & 3) << 5;
    const float* xp = x + (((size_t)(b * 64 + c) * 128 + t) << 7) + f0;
    float* tp = &T[c * 132 + f0];
    #pragma unroll
    for (int j = 0; j < 8; ++j)
      *(float4*)(tp + (j << 2)) = *(const float4*)(xp + (j << 2));
  }
  __syncthreads();
  {
    const int f = tid >> 1, cb = (tid & 1) << 5;
    float* op = x0 + (((size_t)(b * 128 + t) * 128 + f) << 6) + cb;
    #pragma unroll
    for (int j = 0; j < 32; j += 4) {
      float4 v;
      v.x = T[(cb + j + 0) * 132 + f];
      v.y = T[(cb + j + 1) * 132 + f];
      v.z = T[(cb + j + 2) * 132 + f];
      v.w = T[(cb + j + 3) * 132 + f];
      *(float4*)(op + j) = v;
    }
  }
}

// ---------------------------------------------------------------------------
// One block = one (sequence, direction). Chunked-SSD, 16-step chunks at
// (512,4) [2 blocks/CU, occ 40%]. This is the PASSING 126us R8 kernel with
// ONE change (bisect of R9's NaN): P5b (h-update) and P5c (y_intra) merged
// into a single phase — disjoint LDS sets ({sXwT,sBT,sMeta,sH} vs
// {sSm,sXdT,sZx}), so the barrier between them was pure overhead. All bf16
// conversions stay on the proven f2bf (R9's v_cvt_pk asm is the NaN
// suspect and measured slower per guide m240 anyway). 6 barriers/chunk.
// ---------------------------------------------------------------------------
__global__ __launch_bounds__(512, 4) void mamba_dir(
    const float* __restrict__ src,   // [seq][pos][c] f32 (x0 or x1)
    unsigned short* __restrict__ ybuf, // bf16 [dir][seq][pos][64]
    const unsigned short* __restrict__ WpF, // bf16 fragments (4,25600)
    const unsigned short* __restrict__ WcF, // bf16 fragments (4,8192)
    const float* __restrict__ cwA, const float* __restrict__ cbA,
    const float* __restrict__ dtbA, const float* __restrict__ AlA,
    const float* __restrict__ DpA, const float* __restrict__ nwA,
    const float* __restrict__ lnwA, const float* __restrict__ lnbA,
    int phase)
{
  __shared__ __align__(16) unsigned short sU[16 * 72];    // LN'd u (A-frag)
  __shared__ __align__(16) unsigned short sZb[16 * 136];  // z, then g
  __shared__ __align__(16) float sZx[16 * 260];           // raw xBC; y in cols 0-127
  __shared__ __align__(16) unsigned short sBC16[16 * 136];// bf16 B(0-63) C(64-127) row-major
  __shared__ __align__(16) unsigned short sXdT[128 * 40]; // bf16 x^T [c][t], t>=16 zero
  __shared__ __align__(16) unsigned short sXwT[128 * 40]; // bf16 (w_t*x)^T [c][t]
  __shared__ __align__(16) unsigned short sBT[64 * 40];   // bf16 B^T [n][t], t>=16 zero
  __shared__ __align__(16) unsigned short sSm[2 * 16 * 40]; // bf16 masked scores [h][t][s]
  __shared__ __align__(16) unsigned short sH[2 * 64 * 72];  // bf16 h snapshot [h][p][n]
  __shared__ float sMeta[16][2][4];                       // per (t,h): {L, dt, w, P}
  __shared__ float sDtRaw[16][2];

  const int tid = threadIdx.x;
  const int blk = blockIdx.x;
  const int seq = blk >> 1, dir = blk & 1;
  const int ip = (phase << 1) + dir;
  // uniform scalars (SGPR): no VGPR cost
  const float dtb0 = dtbA[ip * 2], dtb1 = dtbA[ip * 2 + 1];
  const float nA0 = -__expf(AlA[ip * 2]), nA1 = -__expf(AlA[ip * 2 + 1]);
  const float Dp0 = DpA[ip * 2], Dp1 = DpA[ip * 2 + 1];
  const int c256 = tid & 255;                 // conv channel
  const int lh = tid >> 8;                    // conv lt-half
  float ch0 = 0.f, ch1 = 0.f, ch2 = 0.f;      // conv carry (lh==0 only)

  const int wv = tid >> 6, lane = tid & 63;
  const int col = lane & 15, quad = lane >> 4;

  f32x4 hacc[4];   // h state: ALL 8 waves, 16 p-channels each (16 regs)
  #pragma unroll
  for (int i = 0; i < 4; ++i) hacc[i] = (f32x4){0.f, 0.f, 0.f, 0.f};

  // zero fragment arrays once: K-pad regions must stay 0; sH = initial state 0
  {
    unsigned int* z;
    z = (unsigned int*)sXdT; for (int i = tid; i < 2560; i += 512) z[i] = 0u;
    z = (unsigned int*)sXwT; for (int i = tid; i < 2560; i += 512) z[i] = 0u;
    z = (unsigned int*)sBT;  for (int i = tid; i < 1280; i += 512) z[i] = 0u;
    z = (unsigned int*)sSm;  for (int i = tid; i < 640;  i += 512) z[i] = 0u;
    z = (unsigned int*)sH;   for (int i = tid; i < 4608; i += 512) z[i] = 0u;
  }

  const unsigned short* wf = WpF + (size_t)ip * 25600;
  const unsigned short* wcf = WcF + (size_t)ip * 8192;
  const size_t sb = (size_t)seq << 13;
  const int pos = tid >> 6, lc = tid & 63;    // load/LN mapping

  // preload chunk 0 (2 floats/thread, coalesced)
  float vc0, vc1;
  {
    const int p0 = dir ? (127 - pos) : pos;
    const int p1 = dir ? (127 - (pos + 8)) : (pos + 8);
    vc0 = src[sb + (size_t)p0 * 64 + lc];
    vc1 = src[sb + (size_t)p1 * 64 + lc];
  }

  for (int ck = 0; ck < 8; ++ck) {
    // ---- prefetch next chunk ----
    float vn0 = 0.f, vn1 = 0.f;
    if (ck < 7) {
      const int st0 = ((ck + 1) << 4) + pos;
      const int p0 = dir ? (127 - st0) : st0;
      const int p1 = dir ? (127 - (st0 + 8)) : (st0 + 8);
      vn0 = src[sb + (size_t)p0 * 64 + lc];
      vn1 = src[sb + (size_t)p1 * 64 + lc];
    }
    // ---- P1: layernorm in registers (wave-shfl), write bf16 sU ----
    {
      const int lnb_i = (phase << 6) + lc;
      const float lnw_v = lnwA[lnb_i], lnb_v = lnbA[lnb_i];
      #pragma unroll
      for (int half = 0; half < 2; ++half) {
        const float v = half ? vc1 : vc0;
        float sm = v, s2 = v * v;
        sm += __shfl_xor(sm, 1);  s2 += __shfl_xor(s2, 1);
        sm += __shfl_xor(sm, 2);  s2 += __shfl_xor(s2, 2);
        sm += __shfl_xor(sm, 4);  s2 += __shfl_xor(s2, 4);
        sm += __shfl_xor(sm, 8);  s2 += __shfl_xor(s2, 8);
        sm += __shfl_xor(sm, 16); s2 += __shfl_xor(s2, 16);
        sm += __shfl_xor(sm, 32); s2 += __shfl_xor(s2, 32);
        const float mean = sm * (1.f / 64.f);
        const float inv = rsqrtf(s2 * (1.f / 64.f) - mean * mean + EPSV);
        sU[(pos + half * 8) * 72 + lc] = f2bf((v - mean) * inv * lnw_v + lnb_v);
      }
    }
    __syncthreads();   // B1
    // ---- P2: in_proj via MFMA; B fragments streamed from global/L2 ----
    {
      const bf16x8 a0 = *(const bf16x8*)(&sU[col * 72 + quad * 8]);
      const bf16x8 a1 = *(const bf16x8*)(&sU[col * 72 + quad * 8 + 32]);
      for (int tile = wv; tile < 25; tile += 8) {
        const unsigned short* wt = wf + (tile << 10) + (lane << 3);
        const bf16x8 b0 = *(const bf16x8*)(wt);
        const bf16x8 b1 = *(const bf16x8*)(wt + 512);
        f32x4 d = {0.f, 0.f, 0.f, 0.f};
        d = __builtin_amdgcn_mfma_f32_16x16x32_bf16(a0, b0, d, 0, 0, 0);
        d = __builtin_amdgcn_mfma_f32_16x16x32_bf16(a1, b1, d, 0, 0, 0);
        const int o = (tile << 4) + col;
        if (tile < 8) {               // z -> bf16
          #pragma unroll
          for (int r = 0; r < 4; ++r)
            sZb[(quad * 4 + r) * 136 + o] = f2bf(d[r]);
        } else if (tile < 24) {       // xBC -> f32
          #pragma unroll
          for (int r = 0; r < 4; ++r)
            sZx[(quad * 4 + r) * 260 + (o - 128)] = d[r];
        } else if (col < 2) {         // dt raw (o = 384,385)
          #pragma unroll
          for (int r = 0; r < 4; ++r)
            sDtRaw[quad * 4 + r][col] = d[r];
        }
      }
    }
    __syncthreads();   // B2
    // ---- P3: conv(4,causal)+silu -> bf16 fragment layouts; dt/L meta ----
    {
      const int c = c256;
      const float4 cw4 = *(const float4*)(cwA + ip * 1024 + (c << 2));
      const float cbias = cbA[ip * 256 + c];
      float a0c, a1c, a2c;
      if (lh == 0) { a0c = ch0; a1c = ch1; a2c = ch2; }
      else {
        a0c = sZx[5 * 260 + c];
        a1c = sZx[6 * 260 + c];
        a2c = sZx[7 * 260 + c];
      }
      const int lt0 = lh << 3;
      unsigned int pkv[4];
      #pragma unroll
      for (int l = 0; l < 8; ++l) {
        const int lt = lt0 + l;
        const float a3 = sZx[lt * 260 + c];
        const float acc = cbias + a0c * cw4.x + a1c * cw4.y + a2c * cw4.z + a3 * cw4.w;
        const float sv = acc * sigmoidf_(acc);
        const unsigned int hv = (unsigned int)f2bf(sv);
        if (c >= 192)      sBC16[lt * 136 + 64 + (c - 192)] = (unsigned short)hv;
        else if (c >= 128) sBC16[lt * 136 + (c - 128)] = (unsigned short)hv;
        if (l & 1) pkv[l >> 1] |= hv << 16; else pkv[l >> 1] = hv;
        a0c = a1c; a1c = a2c; a2c = a3;
      }
      if (c < 128)
        *(uint4*)(&sXdT[c * 40 + lt0]) = make_uint4(pkv[0], pkv[1], pkv[2], pkv[3]);
      else if (c < 192)
        *(uint4*)(&sBT[(c - 128) * 40 + lt0]) = make_uint4(pkv[0], pkv[1], pkv[2], pkv[3]);
      if (lh == 0) {   // carry = raw xBC at lt 13,14,15
        ch0 = sZx[13 * 260 + c];
        ch1 = sZx[14 * 260 + c];
        ch2 = sZx[15 * 260 + c];
      }
      if (tid < 32) {
        const int lt = tid >> 1, hh = tid & 1;
        const float rawv = sDtRaw[lt][hh] + (hh ? dtb1 : dtb0);
        const float dtv = (rawv > 20.f) ? rawv : log1pf(__expf(rawv));
        float Lx = dtv * (hh ? nA1 : nA0);   // log dA_t
        #pragma unroll
        for (int d = 2; d < 32; d <<= 1) {   // inclusive prefix over lt (stride-2 lanes)
          const float tpv = __shfl_up(Lx, d);
          Lx += (tid >= d) ? tpv : 0.f;
        }
        const float Ltot = __shfl(Lx, 30 + hh);
        *(float4*)(&sMeta[lt][hh][0]) =
            make_float4(Lx, dtv, __expf(Ltot - Lx) * dtv, __expf(Lx));
      }
    }
    __syncthreads();   // B3
    // ---- P4: G+mask (w0) | Xw fixup (w1-2) | y_inter -> sZx (w4-7) ----
    if (wv == 0) {
      const bf16x8 ca0 = *(const bf16x8*)(&sBC16[col * 136 + 64 + quad * 8]);
      const bf16x8 ca1 = *(const bf16x8*)(&sBC16[col * 136 + 96 + quad * 8]);
      const bf16x8 bb0 = *(const bf16x8*)(&sBC16[col * 136 + quad * 8]);
      const bf16x8 bb1 = *(const bf16x8*)(&sBC16[col * 136 + 32 + quad * 8]);
      f32x4 g = {0.f, 0.f, 0.f, 0.f};
      g = __builtin_amdgcn_mfma_f32_16x16x32_bf16(ca0, bb0, g, 0, 0, 0);
      g = __builtin_amdgcn_mfma_f32_16x16x32_bf16(ca1, bb1, g, 0, 0, 0);
      // D: row t = quad*4+r, col s = lane&15
      #pragma unroll
      for (int h = 0; h < 2; ++h) {
        const float Ls = sMeta[col][h][0];
        const float dts = sMeta[col][h][1];
        #pragma unroll
        for (int r = 0; r < 4; ++r) {
          const int t = quad * 4 + r;
          const float m = (col <= t) ? __expf(sMeta[t][h][0] - Ls) * dts : 0.f;
          sSm[(h * 16 + t) * 40 + col] = f2bf(g[r] * m);
        }
      }
    } else if (wv <= 2) {
      if (ck < 7) {     // Xw = w_t * x (feeds h-update only)
        const int p = ((wv - 1) << 6) + lane;
        const int hh = p >> 6;
        #pragma unroll
        for (int tp = 0; tp < 8; ++tp) {
          const unsigned int xr = *(const unsigned int*)(&sXdT[p * 40 + tp * 2]);
          const unsigned int lo = (unsigned int)f2bf(bflo(xr) * sMeta[tp * 2][hh][2]);
          const unsigned int hi = (unsigned int)f2bf(bfhi(xr) * sMeta[tp * 2 + 1][hh][2]);
          *(unsigned int*)(&sXwT[p * 40 + tp * 2]) = lo | (hi << 16);
        }
      }
    } else if (wv >= 4) {
      // y_inter[t,c] = P_t * sum_n C[t,n] h_prev[c,n]  -> staged into sZx
      const int h = (wv - 4) >> 1, pt2 = (wv - 4) & 1;
      const int cb0 = h * 64 + pt2 * 32;
      if (ck) {
        const bf16x8 ca0 = *(const bf16x8*)(&sBC16[col * 136 + 64 + quad * 8]);
        const bf16x8 ca1 = *(const bf16x8*)(&sBC16[col * 136 + 96 + quad * 8]);
        #pragma unroll
        for (int half = 0; half < 2; ++half) {
          const unsigned short* hp = &sH[(cb0 + half * 16 + col) * 72];
          const bf16x8 h0 = *(const bf16x8*)(hp + quad * 8);
          const bf16x8 h1 = *(const bf16x8*)(hp + 32 + quad * 8);
          f32x4 d = {0.f, 0.f, 0.f, 0.f};
          d = __builtin_amdgcn_mfma_f32_16x16x32_bf16(ca0, h0, d, 0, 0, 0);
          d = __builtin_amdgcn_mfma_f32_16x16x32_bf16(ca1, h1, d, 0, 0, 0);
          #pragma unroll
          for (int r = 0; r < 4; ++r)
            sZx[(quad * 4 + r) * 260 + cb0 + half * 16 + col] =
                d[r] * sMeta[quad * 4 + r][h][3];
        }
      } else {
        #pragma unroll
        for (int r = 0; r < 4; ++r) {
          sZx[(quad * 4 + r) * 260 + cb0 + col] = 0.f;
          sZx[(quad * 4 + r) * 260 + cb0 + 16 + col] = 0.f;
        }
      }
    }
    __syncthreads();   // B4
    // ---- P5: MERGED — y_intra (C = staged y_inter) + D*x, then h-update +
    //          snapshot (ck<7). Disjoint LDS sets: {sSm,sXdT,sZx} vs
    //          {sXwT,sBT,sMeta,sH}. All 8 waves run both halves. ----
    {
      const int h = wv >> 2;
      const int c = (wv << 4) + col;
      const float dp = h ? Dp1 : Dp0;
      const bf16x8 sa = *(const bf16x8*)(&sSm[(h * 16 + col) * 40 + quad * 8]);
      const bf16x8 xb = *(const bf16x8*)(&sXdT[c * 40 + quad * 8]);
      f32x4 cin;
      #pragma unroll
      for (int r = 0; r < 4; ++r) cin[r] = sZx[(quad * 4 + r) * 260 + c];
      f32x4 yD = __builtin_amdgcn_mfma_f32_16x16x32_bf16(sa, xb, cin, 0, 0, 0);
      const uint2 xw = *(const uint2*)(&sXdT[c * 40 + quad * 4]);
      yD[0] += dp * bflo(xw.x); yD[1] += dp * bfhi(xw.x);
      yD[2] += dp * bflo(xw.y); yD[3] += dp * bfhi(xw.y);
      #pragma unroll
      for (int r = 0; r < 4; ++r)
        sZx[(quad * 4 + r) * 260 + c] = yD[r];

      if (ck < 7) {
        const int pb = wv << 4;
        const float At = sMeta[15][h][3];      // exp(Ltot)
        const bf16x8 xa = *(const bf16x8*)(&sXwT[(pb + col) * 40 + quad * 8]);
        #pragma unroll
        for (int nt = 0; nt < 4; ++nt) {
          const bf16x8 bbt = *(const bf16x8*)(&sBT[(nt * 16 + col) * 40 + quad * 8]);
          #pragma unroll
          for (int r = 0; r < 4; ++r) hacc[nt][r] *= At;
          hacc[nt] = __builtin_amdgcn_mfma_f32_16x16x32_bf16(xa, bbt, hacc[nt], 0, 0, 0);
        }
        #pragma unroll
        for (int nt = 0; nt < 4; ++nt) {
          #pragma unroll
          for (int r = 0; r < 4; ++r)
            sH[(pb + quad * 4 + r) * 72 + nt * 16 + col] = f2bf(hacc[nt][r]);
        }
      }
    }
    __syncthreads();   // B5
    // ---- P6: gate with silu(z) + rmsnorm -> bf16 g IN PLACE over z (sZb) ----
    {
      const int k0 = lc << 1;
      const float2 nw2 = *(const float2*)(nwA + ip * 128 + k0);
      #pragma unroll
      for (int sub = 0; sub < 2; ++sub) {
        const int lt = wv + (sub << 3);
        const float2 yv = *(const float2*)(&sZx[lt * 260 + k0]);
        const unsigned int zp = *(const unsigned int*)(&sZb[lt * 136 + k0]);
        const float z0 = bflo(zp), z1 = bfhi(zp);
        const float g0 = yv.x * (z0 * sigmoidf_(z0));
        const float g1 = yv.y * (z1 * sigmoidf_(z1));
        float ssq = g0 * g0 + g1 * g1;
        ssq += __shfl_xor(ssq, 1);
        ssq += __shfl_xor(ssq, 2);
        ssq += __shfl_xor(ssq, 4);
        ssq += __shfl_xor(ssq, 8);
        ssq += __shfl_xor(ssq, 16);
        ssq += __shfl_xor(ssq, 32);
        const float sc = rsqrtf(ssq * (1.f / 128.f) + EPSV);
        const unsigned int lo = f2bf(g0 * sc * nw2.x);
        const unsigned int hi = f2bf(g1 * sc * nw2.y);
        *(unsigned int*)(&sZb[lt * 136 + k0]) = lo | (hi << 16);
      }
    }
    __syncthreads();   // B6
    // ---- P7: out-matmul via MFMA: g (16x128, A=sZb rows) @ WcF (4 m-tiles) ----
    {
      if (wv < 4) {
        const unsigned short* wt = wcf + (wv << 11);
        f32x4 d = {0.f, 0.f, 0.f, 0.f};
        #pragma unroll
        for (int h = 0; h < 4; ++h) {
          const bf16x8 a = *(const bf16x8*)(&sZb[col * 136 + (h << 5) + (quad << 3)]);
          const bf16x8 bb = *(const bf16x8*)(wt + (h << 9) + (lane << 3));
          d = __builtin_amdgcn_mfma_f32_16x16x32_bf16(a, bb, d, 0, 0, 0);
        }
        const size_t yb = ((size_t)(dir * 512 + seq) * 128) << 6;
        #pragma unroll
        for (int r = 0; r < 4; ++r) {
          const int pp = (quad << 2) + r;
          const int st = (ck << 4) + pp, rp = dir ? (127 - st) : st;
          ybuf[yb + ((size_t)rp << 6) + (wv << 4) + col] = f2bf(d[r]);
        }
      }
    }
    vc0 = vn0; vc1 = vn1;
  }
}

// ---------------------------------------------------------------------------
// combine0: x1[b][f][t][c] = x[b][c][t][f] + yf + yb + fb0[c]   (coalesced)
// ---------------------------------------------------------------------------
__global__ __launch_bounds__(256) void combine0(
    const float* __restrict__ x, const unsigned short* __restrict__ ybuf,
    const float* __restrict__ fb, float* __restrict__ x1)
{
  __shared__ float T[64 * 132];
  const int tid = threadIdx.x, blk = blockIdx.x;
  const int b = blk >> 7, t = blk & 127;
  {
    const int c = tid >> 2, f0 = (tid & 3) << 5;
    const float* xp = x + (((size_t)(b * 64 + c) * 128 + t) << 7) + f0;
    float* tp = &T[c * 132 + f0];
    #pragma unroll
    for (int j = 0; j < 8; ++j)
      *(float4*)(tp + (j << 2)) = *(const float4*)(xp + (j << 2));
  }
  __syncthreads();
  {
    const int f = tid >> 1, cb = (tid & 1) << 5;
    const size_t s0 = (size_t)b * 128 + t;
    const unsigned short* yf = ybuf + ((s0 * 128 + f) << 6) + cb;
    const unsigned short* yb = ybuf + (((s0 + 512) * 128 + f) << 6) + cb;
    float* op = x1 + (((size_t)(b * 128 + f) * 128 + t) << 6) + cb;
    #pragma unroll
    for (int j = 0; j < 32; j += 4) {
      float4 v;
      v.x = T[(cb + j + 0) * 132 + f] + bfu(yf[j + 0]) + bfu(yb[j + 0]) + fb[cb + j + 0];
      v.y = T[(cb + j + 1) * 132 + f] + bfu(yf[j + 1]) + bfu(yb[j + 1]) + fb[cb + j + 1];
      v.z = T[(cb + j + 2) * 132 + f] + bfu(yf[j + 2]) + bfu(yb[j + 2]) + fb[cb + j + 2];
      v.w = T[(cb + j + 3) * 132 + f] + bfu(yf[j + 3]) + bfu(yb[j + 3]) + fb[cb + j + 3];
      *(float4*)(op + j) = v;
    }
  }
}

// ---------------------------------------------------------------------------
// combine1: out[b][c][t][f] = x1[b][f][t][c] + yf + yb + fb1[c]  (coalesced)
// ---------------------------------------------------------------------------
__global__ __launch_bounds__(256) void combine1(
    const float* __restrict__ x1, const unsigned short* __restrict__ ybuf,
    const float* __restrict__ fb, float* __restrict__ out)
{
  __shared__ float T[128 * 68];
  const int tid = threadIdx.x, blk = blockIdx.x;
  const int b = blk >> 7, t = blk & 127;
  {
    const int f = tid >> 1, cb = (tid & 1) << 5;
    const size_t s1 = (size_t)b * 128 + f;
    const float* xp = x1 + ((s1 * 128 + t) << 6) + cb;
    const unsigned short* yf = ybuf + ((s1 * 128 + t) << 6) + cb;
    const unsigned short* yb = ybuf + (((s1 + 512) * 128 + t) << 6) + cb;
    float* tp = &T[f * 68 + cb];
    #pragma unroll
    for (int j = 0; j < 32; j += 4) {
      const float4 xv = *(const float4*)(xp + j);
      const uint2 yfv = *(const uint2*)(yf + j);
      const uint2 ybv = *(const uint2*)(yb + j);
      const float4 fv = *(const float4*)(fb + cb + j);
      tp[j + 0] = xv.x + bflo(yfv.x) + bflo(ybv.x) + fv.x;
      tp[j + 1] = xv.y + bfhi(yfv.x) + bfhi(ybv.x) + fv.y;
      tp[j + 2] = xv.z + bflo(yfv.y) + bflo(ybv.y) + fv.z;
      tp[j + 3] = xv.w + bfhi(yfv.y) + bfhi(ybv.y) + fv.w;
    }
  }
  __syncthreads();
  {
    const int c = tid >> 2, f0 = (tid & 3) << 5;
    float* op = out + (((size_t)(b * 64 + c) * 128 + t) << 7) + f0;
    #pragma unroll
    for (int j = 0; j < 32; j += 4) {
      float4 v;
      v.x = T[(f0 + j + 0) * 68 + c];
      v.y = T[(f0 + j + 1) * 68 + c];
      v.z = T[(f0 + j + 2) * 68 + c];
      v.w = T[(f0 + j + 3) * 68 + c];
      *(float4*)(op + j) = v;
    }
  }
}

extern "C" void kernel_launch(void* const* d_in, const int* in_sizes, int n_in,
                              void* d_out, int out_size, void* d_ws, size_t ws_size,
                              hipStream_t stream) {
  const float* x   = (const float*)d_in[0];
  const float* Wp  = (const float*)d_in[1];
  const float* cw  = (const float*)d_in[2];
  const float* cb  = (const float*)d_in[3];
  const float* dtb = (const float*)d_in[4];
  const float* Al  = (const float*)d_in[5];
  const float* Dp  = (const float*)d_in[6];
  const float* nw  = (const float*)d_in[7];
  const float* oW  = (const float*)d_in[8];
  const float* fW  = (const float*)d_in[9];
  const float* fb  = (const float*)d_in[10];
  const float* lnw = (const float*)d_in[11];
  const float* lnb = (const float*)d_in[12];

  float* ws = (float*)d_ws;
  float* Wc = ws;                                       // 32768 f32
  unsigned short* WpF = (unsigned short*)(ws + 32768);  // 102400 shorts
  unsigned short* WcF = (unsigned short*)(ws + 32768 + 51200); // 32768 shorts
  float* xbuf = ws + 32768 + 51200 + 16384;             // 4194304 f32
  unsigned short* y = (unsigned short*)(xbuf + 4194304); // 8388608 bf16

  precomp_wc<<<32, 256, 0, stream>>>(fW, oW, Wc);
  precomp_wcf<<<4, 256, 0, stream>>>(Wc, WcF);
  precomp_wpf<<<4, 256, 0, stream>>>(Wp, WpF);
  transp0<<<512, 256, 0, stream>>>(x, xbuf);
  mamba_dir<<<1024, 512, 0, stream>>>(xbuf, y, WpF, WcF, cw, cb, dtb, Al, Dp,
                                      nw, lnw, lnb, 0);
  combine0<<<512, 256, 0, stream>>>(x, y, fb, xbuf);
  mamba_dir<<<1024, 512, 0, stream>>>(xbuf, y, WpF, WcF, cw, cb, dtb, Al, Dp,
                                      nw, lnw, lnb, 1);
  combine1<<<512, 256, 0, stream>>>(xbuf, y, fb + 64, (float*)d_out);
}